// Round 1
// baseline (2260.784 us; speedup 1.0000x reference)
//
#include <hip/hip_runtime.h>
#include <hip/hip_bf16.h>

// ---------------------------------------------------------------------------
// GIN0 (GINE x3 + BN + head) forward, fp32.
//   per layer: u = h + scatter_add(relu(h[src] + edge_attr@We + be), dst)
//              t = relu(u@W1 + b1);  r = relu(t@W2 + b2);  h' = BN(r)
//   head: out = relu(h3[last]@Wf1+bf1)@Wf2 + bf2
// ---------------------------------------------------------------------------

__global__ __launch_bounds__(256) void copy_kernel(const float* __restrict__ src,
                                                   float* __restrict__ dst, long n4) {
    long i = (long)blockIdx.x * blockDim.x + threadIdx.x;
    long stride = (long)gridDim.x * blockDim.x;
    const float4* s4 = (const float4*)src;
    float4* d4 = (float4*)dst;
    for (; i < n4; i += stride) d4[i] = s4[i];
}

// One wave per edge (loops over edges). Fuses edge projection (K=16),
// gather of h[src], relu, and atomic scatter-add into u[dst].
template <int D>
__global__ __launch_bounds__(256) void edge_msg_kernel(
    const float* __restrict__ h, const float* __restrict__ ea,
    const int* __restrict__ src, const int* __restrict__ dst,
    const float* __restrict__ We, const float* __restrict__ be,
    float* __restrict__ u, int E) {
    __shared__ float sWe[16 * D];
    __shared__ float sbe[D];
    for (int i = threadIdx.x; i < 16 * D; i += blockDim.x) sWe[i] = We[i];
    for (int i = threadIdx.x; i < D; i += blockDim.x) sbe[i] = be[i];
    __syncthreads();

    const int lane = threadIdx.x & 63;
    const int wid = blockIdx.x * (blockDim.x >> 6) + (threadIdx.x >> 6);
    const int wstride = gridDim.x * (blockDim.x >> 6);

    for (int e = wid; e < E; e += wstride) {
        float eav = (lane < 16) ? ea[(size_t)e * 16 + lane] : 0.0f;
        int s = src[e];
        int d = dst[e];
#pragma unroll
        for (int chunk = 0; chunk < D / 64; ++chunk) {
            int c = chunk * 64 + lane;
            float proj = sbe[c];
#pragma unroll
            for (int k = 0; k < 16; ++k) {
                proj = fmaf(__shfl(eav, k), sWe[k * D + c], proj);
            }
            float m = proj + h[(size_t)s * D + c];
            m = m > 0.0f ? m : 0.0f;
            atomicAdd(&u[(size_t)d * D + c], m);
        }
    }
}

// C[M,N] = act(A[M,K] @ W[K,N] + bias), row-major. BM=BN=64, BK=16,
// 256 threads, 4x4 microtile per thread. N,K multiples of 16 (N mult of 64).
__global__ __launch_bounds__(256) void gemm_bias_act(
    const float* __restrict__ A, const float* __restrict__ W,
    const float* __restrict__ bias, float* __restrict__ C,
    int M, int N, int K, int do_relu) {
    const int BM = 64, BN = 64, BK = 16;
    __shared__ float As[BK][BM];
    __shared__ float Bs[BK][BN];
    int tid = threadIdx.x;
    int bm = blockIdx.y * BM;
    int bn = blockIdx.x * BN;
    int tx = tid & 15, ty = tid >> 4;
    int ar = tid >> 2;           // 0..63 (row within A tile)
    int ak = (tid & 3) * 4;      // 0,4,8,12 (k offset)
    int brw = tid >> 4;          // 0..15 (k row in B tile)
    int bc = (tid & 15) * 4;     // col offset in B tile

    float acc[4][4] = {};
    for (int k0 = 0; k0 < K; k0 += BK) {
        int gr = bm + ar;
        float4 av;
        if (gr < M)
            av = *(const float4*)&A[(size_t)gr * K + k0 + ak];
        else
            av = float4{0.f, 0.f, 0.f, 0.f};
        As[ak + 0][ar] = av.x;
        As[ak + 1][ar] = av.y;
        As[ak + 2][ar] = av.z;
        As[ak + 3][ar] = av.w;
        *(float4*)&Bs[brw][bc] = *(const float4*)&W[(size_t)(k0 + brw) * N + bn + bc];
        __syncthreads();
#pragma unroll
        for (int kk = 0; kk < BK; ++kk) {
            float4 a = *(const float4*)&As[kk][ty * 4];
            float4 b = *(const float4*)&Bs[kk][tx * 4];
            acc[0][0] = fmaf(a.x, b.x, acc[0][0]);
            acc[0][1] = fmaf(a.x, b.y, acc[0][1]);
            acc[0][2] = fmaf(a.x, b.z, acc[0][2]);
            acc[0][3] = fmaf(a.x, b.w, acc[0][3]);
            acc[1][0] = fmaf(a.y, b.x, acc[1][0]);
            acc[1][1] = fmaf(a.y, b.y, acc[1][1]);
            acc[1][2] = fmaf(a.y, b.z, acc[1][2]);
            acc[1][3] = fmaf(a.y, b.w, acc[1][3]);
            acc[2][0] = fmaf(a.z, b.x, acc[2][0]);
            acc[2][1] = fmaf(a.z, b.y, acc[2][1]);
            acc[2][2] = fmaf(a.z, b.z, acc[2][2]);
            acc[2][3] = fmaf(a.z, b.w, acc[2][3]);
            acc[3][0] = fmaf(a.w, b.x, acc[3][0]);
            acc[3][1] = fmaf(a.w, b.y, acc[3][1]);
            acc[3][2] = fmaf(a.w, b.z, acc[3][2]);
            acc[3][3] = fmaf(a.w, b.w, acc[3][3]);
        }
        __syncthreads();
    }
    float4 bb = *(const float4*)&bias[bn + tx * 4];
#pragma unroll
    for (int i = 0; i < 4; ++i) {
        int gr = bm + ty * 4 + i;
        if (gr >= M) continue;
        float4 o;
        o.x = acc[i][0] + bb.x;
        o.y = acc[i][1] + bb.y;
        o.z = acc[i][2] + bb.z;
        o.w = acc[i][3] + bb.w;
        if (do_relu) {
            o.x = fmaxf(o.x, 0.f);
            o.y = fmaxf(o.y, 0.f);
            o.z = fmaxf(o.z, 0.f);
            o.w = fmaxf(o.w, 0.f);
        }
        *(float4*)&C[(size_t)gr * N + bn + tx * 4] = o;
    }
}

// Column sum + sumsq. blockDim.x == D. Each block reduces rowsPerBlock rows.
__global__ void bn_stats_kernel(const float* __restrict__ r, float* __restrict__ sums,
                                int N, int D, int rowsPerBlock) {
    int c = threadIdx.x;
    int row0 = blockIdx.x * rowsPerBlock;
    int row1 = min(row0 + rowsPerBlock, N);
    float s = 0.f, ss = 0.f;
    for (int row = row0; row < row1; ++row) {
        float v = r[(size_t)row * D + c];
        s += v;
        ss = fmaf(v, v, ss);
    }
    atomicAdd(&sums[c], s);
    atomicAdd(&sums[D + c], ss);
}

__global__ __launch_bounds__(256) void bn_apply_kernel(
    float* __restrict__ h, const float* __restrict__ sums,
    const float* __restrict__ g, const float* __restrict__ bt,
    int N, int D, int Dm1) {
    int idx = blockIdx.x * blockDim.x + threadIdx.x;
    int total = N * D;
    int stride = gridDim.x * blockDim.x;
    float invN = 1.0f / (float)N;
    for (; idx < total; idx += stride) {
        int c = idx & Dm1;
        float mu = sums[c] * invN;
        float var = fmaf(-mu, mu, sums[D + c] * invN);
        float sc = rsqrtf(var + 1e-5f) * g[c];
        h[idx] = (h[idx] - mu) * sc + bt[c];
    }
}

__global__ void head_kernel(const float* __restrict__ h, const int* __restrict__ n_nodes,
                            const float* __restrict__ Wf1, const float* __restrict__ bf1,
                            const float* __restrict__ Wf2, const float* __restrict__ bf2,
                            float* __restrict__ out, int G) {
    int g = blockIdx.x * blockDim.x + threadIdx.x;
    if (g >= G) return;
    int s = 0;
    for (int i = 0; i <= g; ++i) s += n_nodes[i];
    const float* m = &h[(size_t)(s - 1) * 64];
    float o = bf2[0];
#pragma unroll 4
    for (int j = 0; j < 16; ++j) {
        float acc = bf1[j];
        for (int k = 0; k < 64; ++k) acc = fmaf(m[k], Wf1[k * 16 + j], acc);
        acc = fmaxf(acc, 0.f);
        o = fmaf(acc, Wf2[j], o);
    }
    out[g] = o;
}

extern "C" void kernel_launch(void* const* d_in, const int* in_sizes, int n_in,
                              void* d_out, int out_size, void* d_ws, size_t ws_size,
                              hipStream_t stream) {
    const float* x = (const float*)d_in[0];
    const float* ea = (const float*)d_in[1];
    const int* eidx = (const int*)d_in[2];
    const int* n_nodes = (const int*)d_in[3];
    const float* We1 = (const float*)d_in[4];
    const float* be1 = (const float*)d_in[5];
    const float* W11 = (const float*)d_in[6];
    const float* b11 = (const float*)d_in[7];
    const float* W12 = (const float*)d_in[8];
    const float* b12 = (const float*)d_in[9];
    const float* g1 = (const float*)d_in[10];
    const float* bt1 = (const float*)d_in[11];
    const float* We2 = (const float*)d_in[12];
    const float* be2 = (const float*)d_in[13];
    const float* W21 = (const float*)d_in[14];
    const float* b21 = (const float*)d_in[15];
    const float* W22 = (const float*)d_in[16];
    const float* b22 = (const float*)d_in[17];
    const float* g2 = (const float*)d_in[18];
    const float* bt2 = (const float*)d_in[19];
    const float* We3 = (const float*)d_in[20];
    const float* be3 = (const float*)d_in[21];
    const float* W31 = (const float*)d_in[22];
    const float* b31 = (const float*)d_in[23];
    const float* W32 = (const float*)d_in[24];
    const float* b32 = (const float*)d_in[25];
    const float* g3 = (const float*)d_in[26];
    const float* bt3 = (const float*)d_in[27];
    const float* Wf1 = (const float*)d_in[28];
    const float* bf1 = (const float*)d_in[29];
    const float* Wf2 = (const float*)d_in[30];
    const float* bf2 = (const float*)d_in[31];

    const int N = in_sizes[0] / 128;  // 50000
    const int E = in_sizes[2] / 2;    // 800000
    const int G = in_sizes[3];        // 500
    const int* srcp = eidx;
    const int* dstp = eidx + E;

    float* A = (float*)d_ws;                 // N x 256 (h / r buffer)
    float* U = A + (size_t)N * 256;          // N x 256 (u = h + agg)
    float* T = U + (size_t)N * 256;          // N x 256 (hidden)
    float* stats1 = T + (size_t)N * 256;     // 512 floats
    float* stats2 = stats1 + 512;            // 256 floats
    float* stats3 = stats2 + 256;            // 128 floats

    hipMemsetAsync(stats1, 0, (512 + 256 + 128) * sizeof(float), stream);

    // ---------------- Layer 1: Cin=128 -> 256 -> 256 ----------------
    copy_kernel<<<1024, 256, 0, stream>>>(x, U, (long)N * 128 / 4);
    edge_msg_kernel<128><<<4096, 256, 0, stream>>>(x, ea, srcp, dstp, We1, be1, U, E);
    {
        dim3 gA(256 / 64, (N + 63) / 64);
        gemm_bias_act<<<gA, 256, 0, stream>>>(U, W11, b11, T, N, 256, 128, 1);
        dim3 gB(256 / 64, (N + 63) / 64);
        gemm_bias_act<<<gB, 256, 0, stream>>>(T, W12, b12, A, N, 256, 256, 1);
    }
    bn_stats_kernel<<<(N + 511) / 512, 256, 0, stream>>>(A, stats1, N, 256, 512);
    bn_apply_kernel<<<2048, 256, 0, stream>>>(A, stats1, g1, bt1, N, 256, 255);

    // ---------------- Layer 2: Cin=256 -> 128 -> 128 ----------------
    copy_kernel<<<1024, 256, 0, stream>>>(A, U, (long)N * 256 / 4);
    edge_msg_kernel<256><<<4096, 256, 0, stream>>>(A, ea, srcp, dstp, We2, be2, U, E);
    {
        dim3 gA(128 / 64, (N + 63) / 64);
        gemm_bias_act<<<gA, 256, 0, stream>>>(U, W21, b21, T, N, 128, 256, 1);
        dim3 gB(128 / 64, (N + 63) / 64);
        gemm_bias_act<<<gB, 256, 0, stream>>>(T, W22, b22, A, N, 128, 128, 1);
    }
    bn_stats_kernel<<<(N + 511) / 512, 128, 0, stream>>>(A, stats2, N, 128, 512);
    bn_apply_kernel<<<2048, 256, 0, stream>>>(A, stats2, g2, bt2, N, 128, 127);

    // ---------------- Layer 3: Cin=128 -> 64 -> 64 ----------------
    copy_kernel<<<1024, 256, 0, stream>>>(A, U, (long)N * 128 / 4);
    edge_msg_kernel<128><<<4096, 256, 0, stream>>>(A, ea, srcp, dstp, We3, be3, U, E);
    {
        dim3 gA(64 / 64, (N + 63) / 64);
        gemm_bias_act<<<gA, 256, 0, stream>>>(U, W31, b31, T, N, 64, 128, 1);
        dim3 gB(64 / 64, (N + 63) / 64);
        gemm_bias_act<<<gB, 256, 0, stream>>>(T, W32, b32, A, N, 64, 64, 1);
    }
    bn_stats_kernel<<<(N + 511) / 512, 64, 0, stream>>>(A, stats3, N, 64, 512);
    bn_apply_kernel<<<2048, 256, 0, stream>>>(A, stats3, g3, bt3, N, 64, 63);

    // ---------------- Head ----------------
    head_kernel<<<(G + 255) / 256, 256, 0, stream>>>(A, n_nodes, Wf1, bf1, Wf2, bf2,
                                                     (float*)d_out, G);
}

// Round 2
// 1740.228 us; speedup vs baseline: 1.2991x; 1.2991x over previous
//
#include <hip/hip_runtime.h>
#include <hip/hip_bf16.h>

// ---------------------------------------------------------------------------
// GIN0 (GINE x3 + BN + head) forward, fp32.
//   per layer: u = h + sum_{e: dst=v} relu(h[src_e] + ea_e@We + be)
//              t = relu(u@W1 + b1);  r = relu(t@W2 + b2);  h' = BN(r)
//   head: out = relu(h3[last]@Wf1+bf1)@Wf2 + bf2
// R1: atomic scatter replaced by CSR (built once per launch) + per-node
//     register aggregation. No atomics in the hot path, writes 16x smaller.
// ---------------------------------------------------------------------------

// ---------------- CSR build ----------------

__global__ __launch_bounds__(256) void hist_kernel(const int* __restrict__ dst,
                                                   int* __restrict__ deg, int E) {
    int i = blockIdx.x * blockDim.x + threadIdx.x;
    int stride = gridDim.x * blockDim.x;
    for (; i < E; i += stride) atomicAdd(&deg[dst[i]], 1);
}

// Single-block exclusive scan of deg[N] -> row_start[N], row_start[N]=total.
__global__ __launch_bounds__(1024) void scan_kernel(const int* __restrict__ deg,
                                                    int* __restrict__ row_start, int N) {
    __shared__ int part[1024];
    __shared__ int total;
    int tid = threadIdx.x;
    int per = (N + 1023) / 1024;
    int start = tid * per;
    int end = min(start + per, N);
    int s = 0;
    for (int i = start; i < end; ++i) s += deg[i];
    part[tid] = s;
    __syncthreads();
    if (tid == 0) {
        int t = 0;
        for (int i = 0; i < 1024; ++i) {
            int v = part[i];
            part[i] = t;
            t += v;
        }
        total = t;
    }
    __syncthreads();
    int run = part[tid];
    for (int i = start; i < end; ++i) {
        row_start[i] = run;
        run += deg[i];
    }
    if (tid == 0) row_start[N] = total;
}

__global__ __launch_bounds__(256) void scatter_kernel(
    const int* __restrict__ src, const int* __restrict__ dst,
    const int* __restrict__ row_start, int* __restrict__ cursor,
    int* __restrict__ csr_eid, int* __restrict__ csr_src, int E) {
    int i = blockIdx.x * blockDim.x + threadIdx.x;
    int stride = gridDim.x * blockDim.x;
    for (; i < E; i += stride) {
        int v = dst[i];
        int p = row_start[v] + atomicAdd(&cursor[v], 1);
        csr_eid[p] = i;
        csr_src[p] = src[i];
    }
}

// ---------------- Fused GINE aggregation (atomic-free) ----------------
// One wave per node: loop in-edges, project edge_attr (K=16 via shuffles),
// gather h[src], relu, accumulate in registers; u[v] = h[v] + acc.
template <int D>
__global__ __launch_bounds__(256) void gine_agg_kernel(
    const float* __restrict__ h, const float* __restrict__ ea,
    const int* __restrict__ row_start, const int* __restrict__ csr_eid,
    const int* __restrict__ csr_src,
    const float* __restrict__ We, const float* __restrict__ be,
    float* __restrict__ u, int N) {
    __shared__ float sWe[16 * D];
    __shared__ float sbe[D];
    for (int i = threadIdx.x; i < 16 * D; i += blockDim.x) sWe[i] = We[i];
    for (int i = threadIdx.x; i < D; i += blockDim.x) sbe[i] = be[i];
    __syncthreads();

    const int lane = threadIdx.x & 63;
    int v = blockIdx.x * (blockDim.x >> 6) + (threadIdx.x >> 6);
    const int vstride = gridDim.x * (blockDim.x >> 6);

    for (; v < N; v += vstride) {
        int e0 = row_start[v];
        int e1 = row_start[v + 1];
        float acc[D / 64];
#pragma unroll
        for (int c = 0; c < D / 64; ++c) acc[c] = 0.f;
        for (int i = e0; i < e1; ++i) {
            int eid = csr_eid[i];
            int s = csr_src[i];
            float eav = (lane < 16) ? ea[(size_t)eid * 16 + lane] : 0.f;
#pragma unroll
            for (int c = 0; c < D / 64; ++c) {
                int ch = c * 64 + lane;
                float proj = sbe[ch];
#pragma unroll
                for (int k = 0; k < 16; ++k)
                    proj = fmaf(__shfl(eav, k), sWe[k * D + ch], proj);
                float m = proj + h[(size_t)s * D + ch];
                acc[c] += fmaxf(m, 0.f);
            }
        }
#pragma unroll
        for (int c = 0; c < D / 64; ++c) {
            int ch = c * 64 + lane;
            u[(size_t)v * D + ch] = h[(size_t)v * D + ch] + acc[c];
        }
    }
}

// ---------------- GEMM (fp32 vector ALU) ----------------
// C[M,N] = act(A[M,K] @ W[K,N] + bias), row-major. BM=BN=64, BK=16,
// 256 threads, 4x4 microtile per thread. N,K multiples of 16 (N mult of 64).
__global__ __launch_bounds__(256) void gemm_bias_act(
    const float* __restrict__ A, const float* __restrict__ W,
    const float* __restrict__ bias, float* __restrict__ C,
    int M, int N, int K, int do_relu) {
    const int BM = 64, BN = 64, BK = 16;
    __shared__ float As[BK][BM];
    __shared__ float Bs[BK][BN];
    int tid = threadIdx.x;
    int bm = blockIdx.y * BM;
    int bn = blockIdx.x * BN;
    int tx = tid & 15, ty = tid >> 4;
    int ar = tid >> 2;
    int ak = (tid & 3) * 4;
    int brw = tid >> 4;
    int bc = (tid & 15) * 4;

    float acc[4][4] = {};
    for (int k0 = 0; k0 < K; k0 += BK) {
        int gr = bm + ar;
        float4 av;
        if (gr < M)
            av = *(const float4*)&A[(size_t)gr * K + k0 + ak];
        else
            av = float4{0.f, 0.f, 0.f, 0.f};
        As[ak + 0][ar] = av.x;
        As[ak + 1][ar] = av.y;
        As[ak + 2][ar] = av.z;
        As[ak + 3][ar] = av.w;
        *(float4*)&Bs[brw][bc] = *(const float4*)&W[(size_t)(k0 + brw) * N + bn + bc];
        __syncthreads();
#pragma unroll
        for (int kk = 0; kk < BK; ++kk) {
            float4 a = *(const float4*)&As[kk][ty * 4];
            float4 b = *(const float4*)&Bs[kk][tx * 4];
            acc[0][0] = fmaf(a.x, b.x, acc[0][0]);
            acc[0][1] = fmaf(a.x, b.y, acc[0][1]);
            acc[0][2] = fmaf(a.x, b.z, acc[0][2]);
            acc[0][3] = fmaf(a.x, b.w, acc[0][3]);
            acc[1][0] = fmaf(a.y, b.x, acc[1][0]);
            acc[1][1] = fmaf(a.y, b.y, acc[1][1]);
            acc[1][2] = fmaf(a.y, b.z, acc[1][2]);
            acc[1][3] = fmaf(a.y, b.w, acc[1][3]);
            acc[2][0] = fmaf(a.z, b.x, acc[2][0]);
            acc[2][1] = fmaf(a.z, b.y, acc[2][1]);
            acc[2][2] = fmaf(a.z, b.z, acc[2][2]);
            acc[2][3] = fmaf(a.z, b.w, acc[2][3]);
            acc[3][0] = fmaf(a.w, b.x, acc[3][0]);
            acc[3][1] = fmaf(a.w, b.y, acc[3][1]);
            acc[3][2] = fmaf(a.w, b.z, acc[3][2]);
            acc[3][3] = fmaf(a.w, b.w, acc[3][3]);
        }
        __syncthreads();
    }
    float4 bb = *(const float4*)&bias[bn + tx * 4];
#pragma unroll
    for (int i = 0; i < 4; ++i) {
        int gr = bm + ty * 4 + i;
        if (gr >= M) continue;
        float4 o;
        o.x = acc[i][0] + bb.x;
        o.y = acc[i][1] + bb.y;
        o.z = acc[i][2] + bb.z;
        o.w = acc[i][3] + bb.w;
        if (do_relu) {
            o.x = fmaxf(o.x, 0.f);
            o.y = fmaxf(o.y, 0.f);
            o.z = fmaxf(o.z, 0.f);
            o.w = fmaxf(o.w, 0.f);
        }
        *(float4*)&C[(size_t)gr * N + bn + tx * 4] = o;
    }
}

// ---------------- BatchNorm ----------------
__global__ void bn_stats_kernel(const float* __restrict__ r, float* __restrict__ sums,
                                int N, int D, int rowsPerBlock) {
    int c = threadIdx.x;
    int row0 = blockIdx.x * rowsPerBlock;
    int row1 = min(row0 + rowsPerBlock, N);
    float s = 0.f, ss = 0.f;
    for (int row = row0; row < row1; ++row) {
        float v = r[(size_t)row * D + c];
        s += v;
        ss = fmaf(v, v, ss);
    }
    atomicAdd(&sums[c], s);
    atomicAdd(&sums[D + c], ss);
}

__global__ __launch_bounds__(256) void bn_apply_kernel(
    float* __restrict__ h, const float* __restrict__ sums,
    const float* __restrict__ g, const float* __restrict__ bt,
    int N, int D, int Dm1) {
    int idx = blockIdx.x * blockDim.x + threadIdx.x;
    int total = N * D;
    int stride = gridDim.x * blockDim.x;
    float invN = 1.0f / (float)N;
    for (; idx < total; idx += stride) {
        int c = idx & Dm1;
        float mu = sums[c] * invN;
        float var = fmaf(-mu, mu, sums[D + c] * invN);
        float sc = rsqrtf(var + 1e-5f) * g[c];
        h[idx] = (h[idx] - mu) * sc + bt[c];
    }
}

// ---------------- Head ----------------
__global__ void head_kernel(const float* __restrict__ h, const int* __restrict__ n_nodes,
                            const float* __restrict__ Wf1, const float* __restrict__ bf1,
                            const float* __restrict__ Wf2, const float* __restrict__ bf2,
                            float* __restrict__ out, int G) {
    int g = blockIdx.x * blockDim.x + threadIdx.x;
    if (g >= G) return;
    int s = 0;
    for (int i = 0; i <= g; ++i) s += n_nodes[i];
    const float* m = &h[(size_t)(s - 1) * 64];
    float o = bf2[0];
#pragma unroll 4
    for (int j = 0; j < 16; ++j) {
        float acc = bf1[j];
        for (int k = 0; k < 64; ++k) acc = fmaf(m[k], Wf1[k * 16 + j], acc);
        acc = fmaxf(acc, 0.f);
        o = fmaf(acc, Wf2[j], o);
    }
    out[g] = o;
}

extern "C" void kernel_launch(void* const* d_in, const int* in_sizes, int n_in,
                              void* d_out, int out_size, void* d_ws, size_t ws_size,
                              hipStream_t stream) {
    const float* x = (const float*)d_in[0];
    const float* ea = (const float*)d_in[1];
    const int* eidx = (const int*)d_in[2];
    const int* n_nodes = (const int*)d_in[3];
    const float* We1 = (const float*)d_in[4];
    const float* be1 = (const float*)d_in[5];
    const float* W11 = (const float*)d_in[6];
    const float* b11 = (const float*)d_in[7];
    const float* W12 = (const float*)d_in[8];
    const float* b12 = (const float*)d_in[9];
    const float* g1 = (const float*)d_in[10];
    const float* bt1 = (const float*)d_in[11];
    const float* We2 = (const float*)d_in[12];
    const float* be2 = (const float*)d_in[13];
    const float* W21 = (const float*)d_in[14];
    const float* b21 = (const float*)d_in[15];
    const float* W22 = (const float*)d_in[16];
    const float* b22 = (const float*)d_in[17];
    const float* g2 = (const float*)d_in[18];
    const float* bt2 = (const float*)d_in[19];
    const float* We3 = (const float*)d_in[20];
    const float* be3 = (const float*)d_in[21];
    const float* W31 = (const float*)d_in[22];
    const float* b31 = (const float*)d_in[23];
    const float* W32 = (const float*)d_in[24];
    const float* b32 = (const float*)d_in[25];
    const float* g3 = (const float*)d_in[26];
    const float* bt3 = (const float*)d_in[27];
    const float* Wf1 = (const float*)d_in[28];
    const float* bf1 = (const float*)d_in[29];
    const float* Wf2 = (const float*)d_in[30];
    const float* bf2 = (const float*)d_in[31];

    const int N = in_sizes[0] / 128;  // 50000
    const int E = in_sizes[2] / 2;    // 800000
    const int G = in_sizes[3];        // 500
    const int* srcp = eidx;
    const int* dstp = eidx + E;

    float* A = (float*)d_ws;              // N x 256 (h / r buffer)
    float* U = A + (size_t)N * 256;       // N x 256 (u = h + agg)
    float* T = U + (size_t)N * 256;       // N x 256 (hidden)
    float* stats1 = T + (size_t)N * 256;  // 512
    float* stats2 = stats1 + 512;         // 256
    float* stats3 = stats2 + 256;         // 128
    int* deg = (int*)(stats3 + 128);      // N (also cursor base)
    int* cursor = deg + N;                // N
    int* row_start = cursor + N;          // N+1
    int* csr_eid = row_start + N + 1;     // E
    int* csr_src = csr_eid + E;           // E

    hipMemsetAsync(stats1, 0, (512 + 256 + 128) * sizeof(float), stream);
    hipMemsetAsync(deg, 0, (size_t)2 * N * sizeof(int), stream);

    // ---------------- CSR build (once, reused by all 3 layers) -------------
    hist_kernel<<<3125, 256, 0, stream>>>(dstp, deg, E);
    scan_kernel<<<1, 1024, 0, stream>>>(deg, row_start, N);
    scatter_kernel<<<3125, 256, 0, stream>>>(srcp, dstp, row_start, cursor,
                                             csr_eid, csr_src, E);

    const int aggBlocks = (N + 3) / 4;

    // ---------------- Layer 1: Cin=128 -> 256 -> 256 ----------------
    gine_agg_kernel<128><<<aggBlocks, 256, 0, stream>>>(x, ea, row_start, csr_eid,
                                                        csr_src, We1, be1, U, N);
    {
        dim3 gA(256 / 64, (N + 63) / 64);
        gemm_bias_act<<<gA, 256, 0, stream>>>(U, W11, b11, T, N, 256, 128, 1);
        dim3 gB(256 / 64, (N + 63) / 64);
        gemm_bias_act<<<gB, 256, 0, stream>>>(T, W12, b12, A, N, 256, 256, 1);
    }
    bn_stats_kernel<<<(N + 511) / 512, 256, 0, stream>>>(A, stats1, N, 256, 512);
    bn_apply_kernel<<<2048, 256, 0, stream>>>(A, stats1, g1, bt1, N, 256, 255);

    // ---------------- Layer 2: Cin=256 -> 128 -> 128 ----------------
    gine_agg_kernel<256><<<aggBlocks, 256, 0, stream>>>(A, ea, row_start, csr_eid,
                                                        csr_src, We2, be2, U, N);
    {
        dim3 gA(128 / 64, (N + 63) / 64);
        gemm_bias_act<<<gA, 256, 0, stream>>>(U, W21, b21, T, N, 128, 256, 1);
        dim3 gB(128 / 64, (N + 63) / 64);
        gemm_bias_act<<<gB, 256, 0, stream>>>(T, W22, b22, A, N, 128, 128, 1);
    }
    bn_stats_kernel<<<(N + 511) / 512, 128, 0, stream>>>(A, stats2, N, 128, 512);
    bn_apply_kernel<<<2048, 256, 0, stream>>>(A, stats2, g2, bt2, N, 128, 127);

    // ---------------- Layer 3: Cin=128 -> 64 -> 64 ----------------
    gine_agg_kernel<128><<<aggBlocks, 256, 0, stream>>>(A, ea, row_start, csr_eid,
                                                        csr_src, We3, be3, U, N);
    {
        dim3 gA(64 / 64, (N + 63) / 64);
        gemm_bias_act<<<gA, 256, 0, stream>>>(U, W31, b31, T, N, 64, 128, 1);
        dim3 gB(64 / 64, (N + 63) / 64);
        gemm_bias_act<<<gB, 256, 0, stream>>>(T, W32, b32, A, N, 64, 64, 1);
    }
    bn_stats_kernel<<<(N + 511) / 512, 64, 0, stream>>>(A, stats3, N, 64, 512);
    bn_apply_kernel<<<2048, 256, 0, stream>>>(A, stats3, g3, bt3, N, 64, 63);

    // ---------------- Head ----------------
    head_kernel<<<(G + 255) / 256, 256, 0, stream>>>(A, n_nodes, Wf1, bf1, Wf2, bf2,
                                                     (float*)d_out, G);
}

// Round 3
// 1384.675 us; speedup vs baseline: 1.6327x; 1.2568x over previous
//
#include <hip/hip_runtime.h>
#include <hip/hip_bf16.h>

// ---------------------------------------------------------------------------
// GIN0 (GINE x3 + BN + head) forward, fp32.
// R1: CSR + per-node register aggregation (no atomics in hot path).
// R2: agg holds We in VGPRs (no LDS), 4-edge unroll for MLP, readlane
//     broadcast for edge features; GEMM 128x64 tile with 8x4 microtile.
// ---------------------------------------------------------------------------

// ---------------- CSR build ----------------

__global__ __launch_bounds__(256) void hist_kernel(const int* __restrict__ dst,
                                                   int* __restrict__ deg, int E) {
    int i = blockIdx.x * blockDim.x + threadIdx.x;
    int stride = gridDim.x * blockDim.x;
    for (; i < E; i += stride) atomicAdd(&deg[dst[i]], 1);
}

__global__ __launch_bounds__(1024) void scan_kernel(const int* __restrict__ deg,
                                                    int* __restrict__ row_start, int N) {
    __shared__ int part[1024];
    int tid = threadIdx.x;
    int per = (N + 1023) / 1024;
    int start = tid * per;
    int end = min(start + per, N);
    int s = 0;
    for (int i = start; i < end; ++i) s += deg[i];
    part[tid] = s;
    __syncthreads();
    if (tid == 0) {
        int t = 0;
        for (int i = 0; i < 1024; ++i) {
            int v = part[i];
            part[i] = t;
            t += v;
        }
    }
    __syncthreads();
    int run = part[tid];
    for (int i = start; i < end; ++i) {
        row_start[i] = run;
        run += deg[i];
    }
    if (tid == 1023) row_start[N] = run;
}

__global__ __launch_bounds__(256) void scatter_kernel(
    const int* __restrict__ src, const int* __restrict__ dst,
    const int* __restrict__ row_start, int* __restrict__ cursor,
    int* __restrict__ csr_eid, int* __restrict__ csr_src, int E) {
    int i = blockIdx.x * blockDim.x + threadIdx.x;
    int stride = gridDim.x * blockDim.x;
    for (; i < E; i += stride) {
        int v = dst[i];
        int p = row_start[v] + atomicAdd(&cursor[v], 1);
        csr_eid[p] = i;
        csr_src[p] = src[i];
    }
}

// ---------------- Fused GINE aggregation ----------------
// One wave per node. We kept in VGPRs (lane L holds columns c*64+L), edge
// features broadcast via v_readlane, 4 edges per iteration for MLP.
template <int D>
__global__ __launch_bounds__(256, 4) void gine_agg_kernel(
    const float* __restrict__ h, const float* __restrict__ ea,
    const int* __restrict__ row_start, const int* __restrict__ csr_eid,
    const int* __restrict__ csr_src,
    const float* __restrict__ We, const float* __restrict__ be,
    float* __restrict__ u, int N) {
    constexpr int C = D / 64;
    const int lane = threadIdx.x & 63;

    float w[16][C];
#pragma unroll
    for (int k = 0; k < 16; ++k)
#pragma unroll
        for (int c = 0; c < C; ++c) w[k][c] = We[k * D + c * 64 + lane];
    float bias[C];
#pragma unroll
    for (int c = 0; c < C; ++c) bias[c] = be[c * 64 + lane];

    int v = blockIdx.x * 4 + (threadIdx.x >> 6);
    const int vstride = gridDim.x * 4;

    for (; v < N; v += vstride) {
        int e0 = row_start[v];
        int e1 = row_start[v + 1];
        float acc[C];
#pragma unroll
        for (int c = 0; c < C; ++c) acc[c] = 0.f;

        int i = e0;
        for (; i + 4 <= e1; i += 4) {
            // edge meta
            int myeid = csr_eid[i + (lane >> 4)];
            float eav = ea[(size_t)myeid * 16 + (lane & 15)];  // 4 edges x 16 feat
            int s0 = csr_src[i + 0];
            int s1 = csr_src[i + 1];
            int s2 = csr_src[i + 2];
            int s3 = csr_src[i + 3];
            float hv[4][C];
#pragma unroll
            for (int c = 0; c < C; ++c) {
                int ch = c * 64 + lane;
                hv[0][c] = h[(size_t)s0 * D + ch];
                hv[1][c] = h[(size_t)s1 * D + ch];
                hv[2][c] = h[(size_t)s2 * D + ch];
                hv[3][c] = h[(size_t)s3 * D + ch];
            }
#pragma unroll
            for (int e = 0; e < 4; ++e) {
                float wk[16];
#pragma unroll
                for (int k = 0; k < 16; ++k)
                    wk[k] = __int_as_float(
                        __builtin_amdgcn_readlane(__float_as_int(eav), e * 16 + k));
#pragma unroll
                for (int c = 0; c < C; ++c) {
                    float p = bias[c];
#pragma unroll
                    for (int k = 0; k < 16; ++k) p = fmaf(wk[k], w[k][c], p);
                    acc[c] += fmaxf(p + hv[e][c], 0.f);
                }
            }
        }
        for (; i < e1; ++i) {  // tail (<=3 edges)
            int eid = csr_eid[i];
            int s = csr_src[i];
            float eav = (lane < 16) ? ea[(size_t)eid * 16 + lane] : 0.f;
            float wk[16];
#pragma unroll
            for (int k = 0; k < 16; ++k)
                wk[k] = __int_as_float(
                    __builtin_amdgcn_readlane(__float_as_int(eav), k));
#pragma unroll
            for (int c = 0; c < C; ++c) {
                int ch = c * 64 + lane;
                float p = bias[c];
#pragma unroll
                for (int k = 0; k < 16; ++k) p = fmaf(wk[k], w[k][c], p);
                acc[c] += fmaxf(p + h[(size_t)s * D + ch], 0.f);
            }
        }
#pragma unroll
        for (int c = 0; c < C; ++c) {
            int ch = c * 64 + lane;
            u[(size_t)v * D + ch] = h[(size_t)v * D + ch] + acc[c];
        }
    }
}

// ---------------- GEMM (fp32 vector ALU) ----------------
// C[M,N] = act(A[M,K] @ W[K,N] + bias). BM=128, BN=64, BK=16, 256 threads,
// 8x4 microtile. N multiple of 64, K multiple of 16.
__global__ __launch_bounds__(256) void gemm_bias_act(
    const float* __restrict__ A, const float* __restrict__ W,
    const float* __restrict__ bias, float* __restrict__ C,
    int M, int N, int K, int do_relu) {
    const int BM = 128, BN = 64, BK = 16;
    __shared__ float As[BK][BM];
    __shared__ float Bs[BK][BN];
    int tid = threadIdx.x;
    int bm = blockIdx.y * BM;
    int bn = blockIdx.x * BN;
    int tx = tid & 15;   // col group: 4 cols
    int ty = tid >> 4;   // row group: 8 rows
    int ar = tid >> 1;          // 0..127
    int ak = (tid & 1) * 8;     // 0 or 8
    int brw = tid >> 4;         // 0..15
    int bc = (tid & 15) * 4;

    float acc[8][4] = {};
    for (int k0 = 0; k0 < K; k0 += BK) {
        int gr = bm + ar;
        float4 av0, av1;
        if (gr < M) {
            const float* Ap = &A[(size_t)gr * K + k0 + ak];
            av0 = *(const float4*)Ap;
            av1 = *(const float4*)(Ap + 4);
        } else {
            av0 = float4{0.f, 0.f, 0.f, 0.f};
            av1 = av0;
        }
        As[ak + 0][ar] = av0.x;
        As[ak + 1][ar] = av0.y;
        As[ak + 2][ar] = av0.z;
        As[ak + 3][ar] = av0.w;
        As[ak + 4][ar] = av1.x;
        As[ak + 5][ar] = av1.y;
        As[ak + 6][ar] = av1.z;
        As[ak + 7][ar] = av1.w;
        *(float4*)&Bs[brw][bc] = *(const float4*)&W[(size_t)(k0 + brw) * N + bn + bc];
        __syncthreads();
#pragma unroll
        for (int kk = 0; kk < BK; ++kk) {
            float4 a0 = *(const float4*)&As[kk][ty * 8];
            float4 a1 = *(const float4*)&As[kk][ty * 8 + 4];
            float4 b = *(const float4*)&Bs[kk][tx * 4];
            float ar_[8] = {a0.x, a0.y, a0.z, a0.w, a1.x, a1.y, a1.z, a1.w};
            float bc_[4] = {b.x, b.y, b.z, b.w};
#pragma unroll
            for (int r = 0; r < 8; ++r)
#pragma unroll
                for (int c = 0; c < 4; ++c) acc[r][c] = fmaf(ar_[r], bc_[c], acc[r][c]);
        }
        __syncthreads();
    }
    float4 bb = *(const float4*)&bias[bn + tx * 4];
    float bbv[4] = {bb.x, bb.y, bb.z, bb.w};
#pragma unroll
    for (int r = 0; r < 8; ++r) {
        int gr = bm + ty * 8 + r;
        if (gr >= M) continue;
        float4 o;
        o.x = acc[r][0] + bbv[0];
        o.y = acc[r][1] + bbv[1];
        o.z = acc[r][2] + bbv[2];
        o.w = acc[r][3] + bbv[3];
        if (do_relu) {
            o.x = fmaxf(o.x, 0.f);
            o.y = fmaxf(o.y, 0.f);
            o.z = fmaxf(o.z, 0.f);
            o.w = fmaxf(o.w, 0.f);
        }
        *(float4*)&C[(size_t)gr * N + bn + tx * 4] = o;
    }
}

// ---------------- BatchNorm ----------------
__global__ void bn_stats_kernel(const float* __restrict__ r, float* __restrict__ sums,
                                int N, int D, int rowsPerBlock) {
    int c = threadIdx.x;
    int row0 = blockIdx.x * rowsPerBlock;
    int row1 = min(row0 + rowsPerBlock, N);
    float s = 0.f, ss = 0.f;
    for (int row = row0; row < row1; ++row) {
        float v = r[(size_t)row * D + c];
        s += v;
        ss = fmaf(v, v, ss);
    }
    atomicAdd(&sums[c], s);
    atomicAdd(&sums[D + c], ss);
}

__global__ __launch_bounds__(256) void bn_apply_kernel(
    float* __restrict__ h, const float* __restrict__ sums,
    const float* __restrict__ g, const float* __restrict__ bt,
    int N, int D, int Dm1) {
    int idx = blockIdx.x * blockDim.x + threadIdx.x;
    int total = N * D;
    int stride = gridDim.x * blockDim.x;
    float invN = 1.0f / (float)N;
    for (; idx < total; idx += stride) {
        int c = idx & Dm1;
        float mu = sums[c] * invN;
        float var = fmaf(-mu, mu, sums[D + c] * invN);
        float sc = rsqrtf(var + 1e-5f) * g[c];
        h[idx] = (h[idx] - mu) * sc + bt[c];
    }
}

// ---------------- Head ----------------
__global__ void head_kernel(const float* __restrict__ h, const int* __restrict__ n_nodes,
                            const float* __restrict__ Wf1, const float* __restrict__ bf1,
                            const float* __restrict__ Wf2, const float* __restrict__ bf2,
                            float* __restrict__ out, int G) {
    int g = blockIdx.x * blockDim.x + threadIdx.x;
    if (g >= G) return;
    int s = 0;
    for (int i = 0; i <= g; ++i) s += n_nodes[i];
    const float* m = &h[(size_t)(s - 1) * 64];
    float o = bf2[0];
#pragma unroll 4
    for (int j = 0; j < 16; ++j) {
        float acc = bf1[j];
        for (int k = 0; k < 64; ++k) acc = fmaf(m[k], Wf1[k * 16 + j], acc);
        acc = fmaxf(acc, 0.f);
        o = fmaf(acc, Wf2[j], o);
    }
    out[g] = o;
}

extern "C" void kernel_launch(void* const* d_in, const int* in_sizes, int n_in,
                              void* d_out, int out_size, void* d_ws, size_t ws_size,
                              hipStream_t stream) {
    const float* x = (const float*)d_in[0];
    const float* ea = (const float*)d_in[1];
    const int* eidx = (const int*)d_in[2];
    const int* n_nodes = (const int*)d_in[3];
    const float* We1 = (const float*)d_in[4];
    const float* be1 = (const float*)d_in[5];
    const float* W11 = (const float*)d_in[6];
    const float* b11 = (const float*)d_in[7];
    const float* W12 = (const float*)d_in[8];
    const float* b12 = (const float*)d_in[9];
    const float* g1 = (const float*)d_in[10];
    const float* bt1 = (const float*)d_in[11];
    const float* We2 = (const float*)d_in[12];
    const float* be2 = (const float*)d_in[13];
    const float* W21 = (const float*)d_in[14];
    const float* b21 = (const float*)d_in[15];
    const float* W22 = (const float*)d_in[16];
    const float* b22 = (const float*)d_in[17];
    const float* g2 = (const float*)d_in[18];
    const float* bt2 = (const float*)d_in[19];
    const float* We3 = (const float*)d_in[20];
    const float* be3 = (const float*)d_in[21];
    const float* W31 = (const float*)d_in[22];
    const float* b31 = (const float*)d_in[23];
    const float* W32 = (const float*)d_in[24];
    const float* b32 = (const float*)d_in[25];
    const float* g3 = (const float*)d_in[26];
    const float* bt3 = (const float*)d_in[27];
    const float* Wf1 = (const float*)d_in[28];
    const float* bf1 = (const float*)d_in[29];
    const float* Wf2 = (const float*)d_in[30];
    const float* bf2 = (const float*)d_in[31];

    const int N = in_sizes[0] / 128;  // 50000
    const int E = in_sizes[2] / 2;    // 800000
    const int G = in_sizes[3];        // 500
    const int* srcp = eidx;
    const int* dstp = eidx + E;

    float* A = (float*)d_ws;              // N x 256
    float* U = A + (size_t)N * 256;       // N x 256
    float* T = U + (size_t)N * 256;       // N x 256
    float* stats1 = T + (size_t)N * 256;  // 512
    float* stats2 = stats1 + 512;         // 256
    float* stats3 = stats2 + 256;         // 128
    int* deg = (int*)(stats3 + 128);      // N
    int* cursor = deg + N;                // N
    int* row_start = cursor + N;          // N+1
    int* csr_eid = row_start + N + 1;     // E
    int* csr_src = csr_eid + E;           // E

    hipMemsetAsync(stats1, 0, (512 + 256 + 128) * sizeof(float), stream);
    hipMemsetAsync(deg, 0, (size_t)2 * N * sizeof(int), stream);

    // ---------------- CSR build ----------------
    hist_kernel<<<3125, 256, 0, stream>>>(dstp, deg, E);
    scan_kernel<<<1, 1024, 0, stream>>>(deg, row_start, N);
    scatter_kernel<<<3125, 256, 0, stream>>>(srcp, dstp, row_start, cursor,
                                             csr_eid, csr_src, E);

    const int aggBlocks = (N + 3) / 4;

    // ---------------- Layer 1: 128 -> 256 -> 256 ----------------
    gine_agg_kernel<128><<<aggBlocks, 256, 0, stream>>>(x, ea, row_start, csr_eid,
                                                        csr_src, We1, be1, U, N);
    {
        dim3 gA(4, (N + 127) / 128);
        gemm_bias_act<<<gA, 256, 0, stream>>>(U, W11, b11, T, N, 256, 128, 1);
        gemm_bias_act<<<gA, 256, 0, stream>>>(T, W12, b12, A, N, 256, 256, 1);
    }
    bn_stats_kernel<<<(N + 511) / 512, 256, 0, stream>>>(A, stats1, N, 256, 512);
    bn_apply_kernel<<<2048, 256, 0, stream>>>(A, stats1, g1, bt1, N, 256, 255);

    // ---------------- Layer 2: 256 -> 128 -> 128 ----------------
    gine_agg_kernel<256><<<aggBlocks, 256, 0, stream>>>(A, ea, row_start, csr_eid,
                                                        csr_src, We2, be2, U, N);
    {
        dim3 gA(2, (N + 127) / 128);
        gemm_bias_act<<<gA, 256, 0, stream>>>(U, W21, b21, T, N, 128, 256, 1);
        gemm_bias_act<<<gA, 256, 0, stream>>>(T, W22, b22, A, N, 128, 128, 1);
    }
    bn_stats_kernel<<<(N + 511) / 512, 128, 0, stream>>>(A, stats2, N, 128, 512);
    bn_apply_kernel<<<2048, 256, 0, stream>>>(A, stats2, g2, bt2, N, 128, 127);

    // ---------------- Layer 3: 128 -> 64 -> 64 ----------------
    gine_agg_kernel<128><<<aggBlocks, 256, 0, stream>>>(A, ea, row_start, csr_eid,
                                                        csr_src, We3, be3, U, N);
    {
        dim3 gA(1, (N + 127) / 128);
        gemm_bias_act<<<gA, 256, 0, stream>>>(U, W31, b31, T, N, 64, 128, 1);
        gemm_bias_act<<<gA, 256, 0, stream>>>(T, W32, b32, A, N, 64, 64, 1);
    }
    bn_stats_kernel<<<(N + 511) / 512, 64, 0, stream>>>(A, stats3, N, 64, 512);
    bn_apply_kernel<<<2048, 256, 0, stream>>>(A, stats3, g3, bt3, N, 64, 63);

    // ---------------- Head ----------------
    head_kernel<<<(G + 255) / 256, 256, 0, stream>>>(A, n_nodes, Wf1, bf1, Wf2, bf2,
                                                     (float*)d_out, G);
}

// Round 4
// 1298.119 us; speedup vs baseline: 1.7416x; 1.0667x over previous
//
#include <hip/hip_runtime.h>
#include <hip/hip_bf16.h>

// ---------------------------------------------------------------------------
// GIN0 (GINE x3 + BN + head) forward.
// R1: CSR + per-node register aggregation (no atomics in hot path).
// R2: We in VGPRs, readlane broadcast, 4-edge unroll.
// R3: node MLP GEMMs on MFMA via split-bf16 (hi+lo, 3-pass) -> fp32-accurate
//     matmul at matrix-core rate. Producers emit bf16 hi/lo pairs directly.
// ---------------------------------------------------------------------------

typedef __attribute__((ext_vector_type(8))) short short8;
typedef __attribute__((ext_vector_type(4))) float floatx4;

__device__ __forceinline__ ushort f2bf_rne(float x) {
    unsigned u = __float_as_uint(x);
    unsigned r = (u + 0x7FFFu + ((u >> 16) & 1u)) >> 16;
    return (ushort)r;
}

// ---------------- CSR build ----------------

__global__ __launch_bounds__(256) void hist_kernel(const int* __restrict__ dst,
                                                   int* __restrict__ deg, int E) {
    int i = blockIdx.x * blockDim.x + threadIdx.x;
    int stride = gridDim.x * blockDim.x;
    for (; i < E; i += stride) atomicAdd(&deg[dst[i]], 1);
}

__global__ __launch_bounds__(1024) void scan_kernel(const int* __restrict__ deg,
                                                    int* __restrict__ row_start, int N) {
    __shared__ int part[1024];
    int tid = threadIdx.x;
    int per = (N + 1023) / 1024;
    int start = tid * per;
    int end = min(start + per, N);
    int s = 0;
    for (int i = start; i < end; ++i) s += deg[i];
    part[tid] = s;
    __syncthreads();
    if (tid == 0) {
        int t = 0;
        for (int i = 0; i < 1024; ++i) {
            int v = part[i];
            part[i] = t;
            t += v;
        }
    }
    __syncthreads();
    int run = part[tid];
    for (int i = start; i < end; ++i) {
        row_start[i] = run;
        run += deg[i];
    }
    if (tid == 1023) row_start[N] = run;
}

__global__ __launch_bounds__(256) void scatter_kernel(
    const int* __restrict__ src, const int* __restrict__ dst,
    const int* __restrict__ row_start, int* __restrict__ cursor,
    int* __restrict__ csr_eid, int* __restrict__ csr_src, int E) {
    int i = blockIdx.x * blockDim.x + threadIdx.x;
    int stride = gridDim.x * blockDim.x;
    for (; i < E; i += stride) {
        int v = dst[i];
        int p = row_start[v] + atomicAdd(&cursor[v], 1);
        csr_eid[p] = i;
        csr_src[p] = src[i];
    }
}

// ---------------- Weight prep: fp32 W[K][N] -> bf16 Wt_hi/lo[N][K] ---------
__global__ __launch_bounds__(256) void prep_weight(const float* __restrict__ W,
                                                   ushort* __restrict__ Wth,
                                                   ushort* __restrict__ Wtl,
                                                   int K, int N) {
    int t = blockIdx.x * blockDim.x + threadIdx.x;
    if (t >= K * N) return;
    int k = t / N, n = t - k * N;
    float v = W[t];
    ushort hv = f2bf_rne(v);
    float hf = __uint_as_float(((unsigned)hv) << 16);
    ushort lv = f2bf_rne(v - hf);
    Wth[(size_t)n * K + k] = hv;
    Wtl[(size_t)n * K + k] = lv;
}

// ---------------- Fused GINE aggregation ----------------
// One wave per node; We in VGPRs; emits u as bf16 hi/lo pair.
template <int D>
__global__ __launch_bounds__(256, 4) void gine_agg_kernel(
    const float* __restrict__ h, const float* __restrict__ ea,
    const int* __restrict__ row_start, const int* __restrict__ csr_eid,
    const int* __restrict__ csr_src,
    const float* __restrict__ We, const float* __restrict__ be,
    ushort* __restrict__ uhi, ushort* __restrict__ ulo, int N) {
    constexpr int C = D / 64;
    const int lane = threadIdx.x & 63;

    float w[16][C];
#pragma unroll
    for (int k = 0; k < 16; ++k)
#pragma unroll
        for (int c = 0; c < C; ++c) w[k][c] = We[k * D + c * 64 + lane];
    float bias[C];
#pragma unroll
    for (int c = 0; c < C; ++c) bias[c] = be[c * 64 + lane];

    int v = blockIdx.x * 4 + (threadIdx.x >> 6);
    const int vstride = gridDim.x * 4;

    for (; v < N; v += vstride) {
        int e0 = row_start[v];
        int e1 = row_start[v + 1];
        float acc[C];
#pragma unroll
        for (int c = 0; c < C; ++c) acc[c] = 0.f;

        int i = e0;
        for (; i + 4 <= e1; i += 4) {
            int myeid = csr_eid[i + (lane >> 4)];
            float eav = ea[(size_t)myeid * 16 + (lane & 15)];
            int s0 = csr_src[i + 0];
            int s1 = csr_src[i + 1];
            int s2 = csr_src[i + 2];
            int s3 = csr_src[i + 3];
            float hv[4][C];
#pragma unroll
            for (int c = 0; c < C; ++c) {
                int ch = c * 64 + lane;
                hv[0][c] = h[(size_t)s0 * D + ch];
                hv[1][c] = h[(size_t)s1 * D + ch];
                hv[2][c] = h[(size_t)s2 * D + ch];
                hv[3][c] = h[(size_t)s3 * D + ch];
            }
#pragma unroll
            for (int e = 0; e < 4; ++e) {
                float wk[16];
#pragma unroll
                for (int k = 0; k < 16; ++k)
                    wk[k] = __int_as_float(
                        __builtin_amdgcn_readlane(__float_as_int(eav), e * 16 + k));
#pragma unroll
                for (int c = 0; c < C; ++c) {
                    float p = bias[c];
#pragma unroll
                    for (int k = 0; k < 16; ++k) p = fmaf(wk[k], w[k][c], p);
                    acc[c] += fmaxf(p + hv[e][c], 0.f);
                }
            }
        }
        for (; i < e1; ++i) {
            int eid = csr_eid[i];
            int s = csr_src[i];
            float eav = (lane < 16) ? ea[(size_t)eid * 16 + lane] : 0.f;
            float wk[16];
#pragma unroll
            for (int k = 0; k < 16; ++k)
                wk[k] = __int_as_float(
                    __builtin_amdgcn_readlane(__float_as_int(eav), k));
#pragma unroll
            for (int c = 0; c < C; ++c) {
                int ch = c * 64 + lane;
                float p = bias[c];
#pragma unroll
                for (int k = 0; k < 16; ++k) p = fmaf(wk[k], w[k][c], p);
                acc[c] += fmaxf(p + h[(size_t)s * D + ch], 0.f);
            }
        }
#pragma unroll
        for (int c = 0; c < C; ++c) {
            int ch = c * 64 + lane;
            float uv = h[(size_t)v * D + ch] + acc[c];
            ushort hvv = f2bf_rne(uv);
            float hf = __uint_as_float(((unsigned)hvv) << 16);
            ushort lvv = f2bf_rne(uv - hf);
            uhi[(size_t)v * D + ch] = hvv;
            ulo[(size_t)v * D + ch] = lvv;
        }
    }
}

// ---------------- Split-bf16 MFMA GEMM ----------------
// C[M,N] = act(A @ W + bias) with A = Ah+Al (M x K bf16 row-major),
// W given transposed+split: Bh/Bl = Wt (N x K bf16 row-major).
// Tile: BM=128, BN=64, BK=64; 256 threads = 4 waves, each 32 rows x 64 cols
// (2x4 frags of 16x16, mfma_f32_16x16x32_bf16, 3 passes hi*hi+hi*lo+lo*hi).
// M is padded to a multiple of 128 by the caller (pad rows are row-isolated).
template <int WRITE_BF16>
__global__ __launch_bounds__(256) void gemm_mfma(
    const ushort* __restrict__ Ah, const ushort* __restrict__ Al,
    const ushort* __restrict__ Bh, const ushort* __restrict__ Bl,
    const float* __restrict__ bias,
    float* __restrict__ Cf, ushort* __restrict__ Chi, ushort* __restrict__ Clo,
    int N, int K, int relu) {
    __shared__ ushort sA[2][128][72];
    __shared__ ushort sB[2][64][72];
    const int tid = threadIdx.x;
    const int wave = tid >> 6, lane = tid & 63;
    const int lrow = lane & 15, lquad = lane >> 4;
    const int bm = blockIdx.y * 128;
    const int bn = blockIdx.x * 64;

    floatx4 acc[2][4];
#pragma unroll
    for (int i = 0; i < 2; ++i)
#pragma unroll
        for (int j = 0; j < 4; ++j) acc[i][j] = (floatx4)0.f;

    for (int k0 = 0; k0 < K; k0 += 64) {
        for (int s = tid; s < 1024; s += 256) {
            int row = s >> 3, c8 = (s & 7) * 8;
            size_t g = (size_t)(bm + row) * K + k0 + c8;
            *(int4*)&sA[0][row][c8] = *(const int4*)&Ah[g];
            *(int4*)&sA[1][row][c8] = *(const int4*)&Al[g];
        }
        for (int s = tid; s < 512; s += 256) {
            int row = s >> 3, c8 = (s & 7) * 8;
            size_t g = (size_t)(bn + row) * K + k0 + c8;
            *(int4*)&sB[0][row][c8] = *(const int4*)&Bh[g];
            *(int4*)&sB[1][row][c8] = *(const int4*)&Bl[g];
        }
        __syncthreads();
        const int rb = wave * 32;
#pragma unroll
        for (int kk = 0; kk < 2; ++kk) {
            int ko = kk * 32 + lquad * 8;
            short8 ah[2], al[2], bh[4], bl[4];
#pragma unroll
            for (int i = 0; i < 2; ++i) {
                ah[i] = *(const short8*)&sA[0][rb + i * 16 + lrow][ko];
                al[i] = *(const short8*)&sA[1][rb + i * 16 + lrow][ko];
            }
#pragma unroll
            for (int j = 0; j < 4; ++j) {
                bh[j] = *(const short8*)&sB[0][j * 16 + lrow][ko];
                bl[j] = *(const short8*)&sB[1][j * 16 + lrow][ko];
            }
#pragma unroll
            for (int i = 0; i < 2; ++i)
#pragma unroll
                for (int j = 0; j < 4; ++j) {
                    acc[i][j] = __builtin_amdgcn_mfma_f32_16x16x32_bf16(
                        ah[i], bh[j], acc[i][j], 0, 0, 0);
                    acc[i][j] = __builtin_amdgcn_mfma_f32_16x16x32_bf16(
                        ah[i], bl[j], acc[i][j], 0, 0, 0);
                    acc[i][j] = __builtin_amdgcn_mfma_f32_16x16x32_bf16(
                        al[i], bh[j], acc[i][j], 0, 0, 0);
                }
        }
        __syncthreads();
    }
#pragma unroll
    for (int i = 0; i < 2; ++i)
#pragma unroll
        for (int j = 0; j < 4; ++j) {
            int gc = bn + j * 16 + lrow;
            float bv = bias[gc];
#pragma unroll
            for (int r = 0; r < 4; ++r) {
                int gr = bm + wave * 32 + i * 16 + lquad * 4 + r;
                float v = acc[i][j][r] + bv;
                if (relu) v = fmaxf(v, 0.f);
                if (WRITE_BF16) {
                    ushort hv = f2bf_rne(v);
                    float hf = __uint_as_float(((unsigned)hv) << 16);
                    ushort lv = f2bf_rne(v - hf);
                    Chi[(size_t)gr * N + gc] = hv;
                    Clo[(size_t)gr * N + gc] = lv;
                } else {
                    Cf[(size_t)gr * N + gc] = v;
                }
            }
        }
}

// ---------------- BatchNorm ----------------
__global__ void bn_stats_kernel(const float* __restrict__ r, float* __restrict__ sums,
                                int N, int D, int rowsPerBlock) {
    int c = threadIdx.x;
    int row0 = blockIdx.x * rowsPerBlock;
    int row1 = min(row0 + rowsPerBlock, N);
    float s = 0.f, ss = 0.f;
    for (int row = row0; row < row1; ++row) {
        float v = r[(size_t)row * D + c];
        s += v;
        ss = fmaf(v, v, ss);
    }
    atomicAdd(&sums[c], s);
    atomicAdd(&sums[D + c], ss);
}

__global__ __launch_bounds__(256) void bn_apply_kernel(
    const float* __restrict__ r, float* __restrict__ h,
    const float* __restrict__ sums,
    const float* __restrict__ g, const float* __restrict__ bt,
    int N, int D, int Dm1) {
    int idx = blockIdx.x * blockDim.x + threadIdx.x;
    int total = N * D;
    int stride = gridDim.x * blockDim.x;
    float invN = 1.0f / (float)N;
    for (; idx < total; idx += stride) {
        int c = idx & Dm1;
        float mu = sums[c] * invN;
        float var = fmaf(-mu, mu, sums[D + c] * invN);
        float sc = rsqrtf(var + 1e-5f) * g[c];
        h[idx] = (r[idx] - mu) * sc + bt[c];
    }
}

// ---------------- Head ----------------
__global__ void head_kernel(const float* __restrict__ h, const int* __restrict__ n_nodes,
                            const float* __restrict__ Wf1, const float* __restrict__ bf1,
                            const float* __restrict__ Wf2, const float* __restrict__ bf2,
                            float* __restrict__ out, int G) {
    int g = blockIdx.x * blockDim.x + threadIdx.x;
    if (g >= G) return;
    int s = 0;
    for (int i = 0; i <= g; ++i) s += n_nodes[i];
    const float* m = &h[(size_t)(s - 1) * 64];
    float o = bf2[0];
#pragma unroll 4
    for (int j = 0; j < 16; ++j) {
        float acc = bf1[j];
        for (int k = 0; k < 64; ++k) acc = fmaf(m[k], Wf1[k * 16 + j], acc);
        acc = fmaxf(acc, 0.f);
        o = fmaf(acc, Wf2[j], o);
    }
    out[g] = o;
}

extern "C" void kernel_launch(void* const* d_in, const int* in_sizes, int n_in,
                              void* d_out, int out_size, void* d_ws, size_t ws_size,
                              hipStream_t stream) {
    const float* x = (const float*)d_in[0];
    const float* ea = (const float*)d_in[1];
    const int* eidx = (const int*)d_in[2];
    const int* n_nodes = (const int*)d_in[3];
    const float* We1 = (const float*)d_in[4];
    const float* be1 = (const float*)d_in[5];
    const float* W11 = (const float*)d_in[6];
    const float* b11 = (const float*)d_in[7];
    const float* W12 = (const float*)d_in[8];
    const float* b12 = (const float*)d_in[9];
    const float* g1 = (const float*)d_in[10];
    const float* bt1 = (const float*)d_in[11];
    const float* We2 = (const float*)d_in[12];
    const float* be2 = (const float*)d_in[13];
    const float* W21 = (const float*)d_in[14];
    const float* b21 = (const float*)d_in[15];
    const float* W22 = (const float*)d_in[16];
    const float* b22 = (const float*)d_in[17];
    const float* g2 = (const float*)d_in[18];
    const float* bt2 = (const float*)d_in[19];
    const float* We3 = (const float*)d_in[20];
    const float* be3 = (const float*)d_in[21];
    const float* W31 = (const float*)d_in[22];
    const float* b31 = (const float*)d_in[23];
    const float* W32 = (const float*)d_in[24];
    const float* b32 = (const float*)d_in[25];
    const float* g3 = (const float*)d_in[26];
    const float* bt3 = (const float*)d_in[27];
    const float* Wf1 = (const float*)d_in[28];
    const float* bf1 = (const float*)d_in[29];
    const float* Wf2 = (const float*)d_in[30];
    const float* bf2 = (const float*)d_in[31];

    const int N = in_sizes[0] / 128;  // 50000
    const int E = in_sizes[2] / 2;    // 800000
    const int G = in_sizes[3];        // 500
    const int Mp = ((N + 127) / 128) * 128;  // 50048 (row-padded for GEMM)
    const int* srcp = eidx;
    const int* dstp = eidx + E;

    float* H = (float*)d_ws;                // Mp x 256 fp32
    float* UR = H + (size_t)Mp * 256;       // Mp x 256 region: u(hi/lo bf16) then r(fp32)
    float* TT = UR + (size_t)Mp * 256;      // Mp x 256 region: t(hi/lo bf16)
    float* stats1 = TT + (size_t)Mp * 256;  // 512
    float* stats2 = stats1 + 512;           // 256
    float* stats3 = stats2 + 256;           // 128
    ushort* wp = (ushort*)(stats3 + 128);
    ushort* W11th = wp; wp += 128 * 256;
    ushort* W11tl = wp; wp += 128 * 256;
    ushort* W12th = wp; wp += 256 * 256;
    ushort* W12tl = wp; wp += 256 * 256;
    ushort* W21th = wp; wp += 256 * 128;
    ushort* W21tl = wp; wp += 256 * 128;
    ushort* W22th = wp; wp += 128 * 128;
    ushort* W22tl = wp; wp += 128 * 128;
    ushort* W31th = wp; wp += 128 * 64;
    ushort* W31tl = wp; wp += 128 * 64;
    ushort* W32th = wp; wp += 64 * 64;
    ushort* W32tl = wp; wp += 64 * 64;
    int* deg = (int*)wp;               // N
    int* cursor = deg + N;             // N
    int* row_start = cursor + N;       // N+1
    int* csr_eid = row_start + N + 1;  // E
    int* csr_src = csr_eid + E;        // E

    hipMemsetAsync(stats1, 0, (512 + 256 + 128) * sizeof(float), stream);
    hipMemsetAsync(deg, 0, (size_t)2 * N * sizeof(int), stream);

    // ---------------- Weight prep ----------------
    prep_weight<<<(128 * 256 + 255) / 256, 256, 0, stream>>>(W11, W11th, W11tl, 128, 256);
    prep_weight<<<(256 * 256 + 255) / 256, 256, 0, stream>>>(W12, W12th, W12tl, 256, 256);
    prep_weight<<<(256 * 128 + 255) / 256, 256, 0, stream>>>(W21, W21th, W21tl, 256, 128);
    prep_weight<<<(128 * 128 + 255) / 256, 256, 0, stream>>>(W22, W22th, W22tl, 128, 128);
    prep_weight<<<(128 * 64 + 255) / 256, 256, 0, stream>>>(W31, W31th, W31tl, 128, 64);
    prep_weight<<<(64 * 64 + 255) / 256, 256, 0, stream>>>(W32, W32th, W32tl, 64, 64);

    // ---------------- CSR build ----------------
    hist_kernel<<<3125, 256, 0, stream>>>(dstp, deg, E);
    scan_kernel<<<1, 1024, 0, stream>>>(deg, row_start, N);
    scatter_kernel<<<3125, 256, 0, stream>>>(srcp, dstp, row_start, cursor,
                                             csr_eid, csr_src, E);

    const int aggBlocks = (N + 3) / 4;
    const int gy = Mp / 128;
    float* R = UR;

    // ---------------- Layer 1: 128 -> 256 -> 256 ----------------
    {
        ushort* Uhi = (ushort*)UR; ushort* Ulo = Uhi + (size_t)Mp * 128;
        ushort* Thi = (ushort*)TT; ushort* Tlo = Thi + (size_t)Mp * 256;
        gine_agg_kernel<128><<<aggBlocks, 256, 0, stream>>>(
            x, ea, row_start, csr_eid, csr_src, We1, be1, Uhi, Ulo, N);
        gemm_mfma<1><<<dim3(4, gy), 256, 0, stream>>>(
            Uhi, Ulo, W11th, W11tl, b11, nullptr, Thi, Tlo, 256, 128, 1);
        gemm_mfma<0><<<dim3(4, gy), 256, 0, stream>>>(
            Thi, Tlo, W12th, W12tl, b12, R, nullptr, nullptr, 256, 256, 1);
        bn_stats_kernel<<<(N + 511) / 512, 256, 0, stream>>>(R, stats1, N, 256, 512);
        bn_apply_kernel<<<2048, 256, 0, stream>>>(R, H, stats1, g1, bt1, N, 256, 255);
    }

    // ---------------- Layer 2: 256 -> 128 -> 128 ----------------
    {
        ushort* Uhi = (ushort*)UR; ushort* Ulo = Uhi + (size_t)Mp * 256;
        ushort* Thi = (ushort*)TT; ushort* Tlo = Thi + (size_t)Mp * 128;
        gine_agg_kernel<256><<<aggBlocks, 256, 0, stream>>>(
            H, ea, row_start, csr_eid, csr_src, We2, be2, Uhi, Ulo, N);
        gemm_mfma<1><<<dim3(2, gy), 256, 0, stream>>>(
            Uhi, Ulo, W21th, W21tl, b21, nullptr, Thi, Tlo, 128, 256, 1);
        gemm_mfma<0><<<dim3(2, gy), 256, 0, stream>>>(
            Thi, Tlo, W22th, W22tl, b22, R, nullptr, nullptr, 128, 128, 1);
        bn_stats_kernel<<<(N + 511) / 512, 128, 0, stream>>>(R, stats2, N, 128, 512);
        bn_apply_kernel<<<2048, 256, 0, stream>>>(R, H, stats2, g2, bt2, N, 128, 127);
    }

    // ---------------- Layer 3: 128 -> 64 -> 64 ----------------
    {
        ushort* Uhi = (ushort*)UR; ushort* Ulo = Uhi + (size_t)Mp * 128;
        ushort* Thi = (ushort*)TT; ushort* Tlo = Thi + (size_t)Mp * 64;
        gine_agg_kernel<128><<<aggBlocks, 256, 0, stream>>>(
            H, ea, row_start, csr_eid, csr_src, We3, be3, Uhi, Ulo, N);
        gemm_mfma<1><<<dim3(1, gy), 256, 0, stream>>>(
            Uhi, Ulo, W31th, W31tl, b31, nullptr, Thi, Tlo, 64, 128, 1);
        gemm_mfma<0><<<dim3(1, gy), 256, 0, stream>>>(
            Thi, Tlo, W32th, W32tl, b32, R, nullptr, nullptr, 64, 64, 1);
        bn_stats_kernel<<<(N + 511) / 512, 64, 0, stream>>>(R, stats3, N, 64, 512);
        bn_apply_kernel<<<2048, 256, 0, stream>>>(R, H, stats3, g3, bt3, N, 64, 63);
    }

    // ---------------- Head ----------------
    head_kernel<<<(G + 255) / 256, 256, 0, stream>>>(H, n_nodes, Wf1, bf1, Wf2, bf2,
                                                     (float*)d_out, G);
}

// Round 5
// 1055.448 us; speedup vs baseline: 2.1420x; 1.2299x over previous
//
#include <hip/hip_runtime.h>
#include <hip/hip_bf16.h>

// ---------------------------------------------------------------------------
// GIN0 (GINE x3 + BN + head) forward.
// R1: CSR + per-node register aggregation (no atomics in hot path).
// R2: We in VGPRs, readlane broadcast, 4-edge unroll.
// R3: node MLP GEMMs on MFMA via split-bf16 (hi+lo, 3-pass).
// R5: agg pinned to 4 waves/EU (128 VGPR cap -> We truly resident; the R4
//     compiler chose 64 VGPR and rematerialized We -> FETCH 452MB),
//     float2/pk_fma channel math; BN stats fused into GEMM2 epilogue;
//     single prep kernel + single memset.
// ---------------------------------------------------------------------------

typedef __attribute__((ext_vector_type(8))) short short8;
typedef __attribute__((ext_vector_type(4))) float floatx4;
typedef __attribute__((ext_vector_type(2))) float float2v;

__device__ __forceinline__ float2v splat2(float s) {
    float2v v;
    v[0] = s;
    v[1] = s;
    return v;
}

__device__ __forceinline__ ushort f2bf_rne(float x) {
    unsigned u = __float_as_uint(x);
    unsigned r = (u + 0x7FFFu + ((u >> 16) & 1u)) >> 16;
    return (ushort)r;
}

// ---------------- CSR build ----------------

__global__ __launch_bounds__(256) void hist_kernel(const int* __restrict__ dst,
                                                   int* __restrict__ deg, int E) {
    int i = blockIdx.x * blockDim.x + threadIdx.x;
    int stride = gridDim.x * blockDim.x;
    for (; i < E; i += stride) atomicAdd(&deg[dst[i]], 1);
}

__global__ __launch_bounds__(1024) void scan_kernel(const int* __restrict__ deg,
                                                    int* __restrict__ row_start, int N) {
    __shared__ int part[1024];
    int tid = threadIdx.x;
    int per = (N + 1023) / 1024;
    int start = tid * per;
    int end = min(start + per, N);
    int s = 0;
    for (int i = start; i < end; ++i) s += deg[i];
    part[tid] = s;
    __syncthreads();
    if (tid == 0) {
        int t = 0;
        for (int i = 0; i < 1024; ++i) {
            int v = part[i];
            part[i] = t;
            t += v;
        }
    }
    __syncthreads();
    int run = part[tid];
    for (int i = start; i < end; ++i) {
        row_start[i] = run;
        run += deg[i];
    }
    if (tid == 1023) row_start[N] = run;
}

__global__ __launch_bounds__(256) void scatter_kernel(
    const int* __restrict__ src, const int* __restrict__ dst,
    const int* __restrict__ row_start, int* __restrict__ cursor,
    int* __restrict__ csr_eid, int* __restrict__ csr_src, int E) {
    int i = blockIdx.x * blockDim.x + threadIdx.x;
    int stride = gridDim.x * blockDim.x;
    for (; i < E; i += stride) {
        int v = dst[i];
        int p = row_start[v] + atomicAdd(&cursor[v], 1);
        csr_eid[p] = i;
        csr_src[p] = src[i];
    }
}

// ---------------- Weight prep: all 6 weights in one launch ----------------
__device__ __forceinline__ void wsplit(const float* W, ushort* Wth, ushort* Wtl,
                                       int K, int N, int t) {
    int k = t / N, n = t - k * N;
    float v = W[t];
    ushort hv = f2bf_rne(v);
    float hf = __uint_as_float(((unsigned)hv) << 16);
    ushort lv = f2bf_rne(v - hf);
    Wth[(size_t)n * K + k] = hv;
    Wtl[(size_t)n * K + k] = lv;
}

__global__ __launch_bounds__(256) void prep_all(
    const float* W11, ushort* W11h, ushort* W11l,
    const float* W12, ushort* W12h, ushort* W12l,
    const float* W21, ushort* W21h, ushort* W21l,
    const float* W22, ushort* W22h, ushort* W22l,
    const float* W31, ushort* W31h, ushort* W31l,
    const float* W32, ushort* W32h, ushort* W32l) {
    int t = blockIdx.x * blockDim.x + threadIdx.x;
    const int s1 = 128 * 256, s2 = s1 + 256 * 256, s3 = s2 + 256 * 128;
    const int s4 = s3 + 128 * 128, s5 = s4 + 128 * 64, s6 = s5 + 64 * 64;
    if (t < s1) wsplit(W11, W11h, W11l, 128, 256, t);
    else if (t < s2) wsplit(W12, W12h, W12l, 256, 256, t - s1);
    else if (t < s3) wsplit(W21, W21h, W21l, 256, 128, t - s2);
    else if (t < s4) wsplit(W22, W22h, W22l, 128, 128, t - s3);
    else if (t < s5) wsplit(W31, W31h, W31l, 128, 64, t - s4);
    else if (t < s6) wsplit(W32, W32h, W32l, 64, 64, t - s5);
}

// ---------------- Fused GINE aggregation ----------------
// One wave per node; We resident in VGPRs (pinned 4 waves/EU -> 128 VGPR cap);
// float2 channel math (pk_fma); emits u as bf16 hi/lo pairs.
template <int D>
__global__ __launch_bounds__(256)
__attribute__((amdgpu_waves_per_eu(4, 4))) void gine_agg_kernel(
    const float* __restrict__ h, const float* __restrict__ ea,
    const int* __restrict__ row_start, const int* __restrict__ csr_eid,
    const int* __restrict__ csr_src,
    const float* __restrict__ We, const float* __restrict__ be,
    ushort* __restrict__ uhi, ushort* __restrict__ ulo, int N) {
    constexpr int C2 = D / 128;  // float2 chunks per lane
    const int lane = threadIdx.x & 63;

    float2v w[16][C2];
#pragma unroll
    for (int k = 0; k < 16; ++k)
#pragma unroll
        for (int c = 0; c < C2; ++c)
            w[k][c] = ((const float2v*)&We[k * D])[c * 64 + lane];
    float2v bias[C2];
#pragma unroll
    for (int c = 0; c < C2; ++c) bias[c] = ((const float2v*)be)[c * 64 + lane];

    int v = blockIdx.x * 4 + (threadIdx.x >> 6);
    const int vstride = gridDim.x * 4;
    const float2v z2 = splat2(0.f);

    for (; v < N; v += vstride) {
        int e0 = row_start[v];
        int e1 = row_start[v + 1];
        float2v acc[C2];
#pragma unroll
        for (int c = 0; c < C2; ++c) acc[c] = z2;

        int i = e0;
        for (; i + 4 <= e1; i += 4) {
            int myeid = csr_eid[i + (lane >> 4)];
            float eav = ea[(size_t)myeid * 16 + (lane & 15)];
            int s0 = csr_src[i + 0];
            int s1 = csr_src[i + 1];
            int s2 = csr_src[i + 2];
            int s3 = csr_src[i + 3];
            float2v hv[4][C2];
#pragma unroll
            for (int c = 0; c < C2; ++c) {
                int idx = c * 64 + lane;
                hv[0][c] = ((const float2v*)(h + (size_t)s0 * D))[idx];
                hv[1][c] = ((const float2v*)(h + (size_t)s1 * D))[idx];
                hv[2][c] = ((const float2v*)(h + (size_t)s2 * D))[idx];
                hv[3][c] = ((const float2v*)(h + (size_t)s3 * D))[idx];
            }
#pragma unroll
            for (int e = 0; e < 4; ++e) {
                float wk[16];
#pragma unroll
                for (int k = 0; k < 16; ++k)
                    wk[k] = __int_as_float(
                        __builtin_amdgcn_readlane(__float_as_int(eav), e * 16 + k));
#pragma unroll
                for (int c = 0; c < C2; ++c) {
                    float2v p = bias[c];
#pragma unroll
                    for (int k = 0; k < 16; ++k)
                        p = __builtin_elementwise_fma(splat2(wk[k]), w[k][c], p);
                    float2v m = p + hv[e][c];
                    acc[c] += __builtin_elementwise_max(m, z2);
                }
            }
        }
        for (; i < e1; ++i) {
            int eid = csr_eid[i];
            int s = csr_src[i];
            float eav = (lane < 16) ? ea[(size_t)eid * 16 + lane] : 0.f;
            float wk[16];
#pragma unroll
            for (int k = 0; k < 16; ++k)
                wk[k] = __int_as_float(
                    __builtin_amdgcn_readlane(__float_as_int(eav), k));
#pragma unroll
            for (int c = 0; c < C2; ++c) {
                float2v p = bias[c];
#pragma unroll
                for (int k = 0; k < 16; ++k)
                    p = __builtin_elementwise_fma(splat2(wk[k]), w[k][c], p);
                float2v m = p + ((const float2v*)(h + (size_t)s * D))[c * 64 + lane];
                acc[c] += __builtin_elementwise_max(m, z2);
            }
        }
#pragma unroll
        for (int c = 0; c < C2; ++c) {
            float2v uv = ((const float2v*)(h + (size_t)v * D))[c * 64 + lane] + acc[c];
            ushort h0 = f2bf_rne(uv[0]);
            ushort h1 = f2bf_rne(uv[1]);
            float hf0 = __uint_as_float(((unsigned)h0) << 16);
            float hf1 = __uint_as_float(((unsigned)h1) << 16);
            ushort l0 = f2bf_rne(uv[0] - hf0);
            ushort l1 = f2bf_rne(uv[1] - hf1);
            size_t o = (size_t)v * D + c * 128 + lane * 2;
            *(ushort2*)&uhi[o] = make_ushort2(h0, h1);
            *(ushort2*)&ulo[o] = make_ushort2(l0, l1);
        }
    }
}

// ---------------- Split-bf16 MFMA GEMM (+ optional fused BN stats) ---------
// C[M,N] = act(A @ W + bias); A = Ah+Al (MxK bf16 rm), W transposed+split
// (NxK bf16 rm). BM=128, BN=64, BK=64; 4 waves, 2x4 16x16 frags, 3 passes.
// STATS: per-column sum/sumsq of the stored (post-relu) value, rows < Nreal.
template <int WRITE_BF16, int STATS>
__global__ __launch_bounds__(256) void gemm_mfma(
    const ushort* __restrict__ Ah, const ushort* __restrict__ Al,
    const ushort* __restrict__ Bh, const ushort* __restrict__ Bl,
    const float* __restrict__ bias,
    float* __restrict__ Cf, ushort* __restrict__ Chi, ushort* __restrict__ Clo,
    float* __restrict__ stats, int Nreal,
    int N, int K, int relu) {
    __shared__ ushort sA[2][128][72];
    __shared__ ushort sB[2][64][72];
    const int tid = threadIdx.x;
    const int wave = tid >> 6, lane = tid & 63;
    const int lrow = lane & 15, lquad = lane >> 4;
    const int bm = blockIdx.y * 128;
    const int bn = blockIdx.x * 64;

    floatx4 acc[2][4];
#pragma unroll
    for (int i = 0; i < 2; ++i)
#pragma unroll
        for (int j = 0; j < 4; ++j) acc[i][j] = (floatx4)0.f;

    for (int k0 = 0; k0 < K; k0 += 64) {
        for (int s = tid; s < 1024; s += 256) {
            int row = s >> 3, c8 = (s & 7) * 8;
            size_t g = (size_t)(bm + row) * K + k0 + c8;
            *(int4*)&sA[0][row][c8] = *(const int4*)&Ah[g];
            *(int4*)&sA[1][row][c8] = *(const int4*)&Al[g];
        }
        for (int s = tid; s < 512; s += 256) {
            int row = s >> 3, c8 = (s & 7) * 8;
            size_t g = (size_t)(bn + row) * K + k0 + c8;
            *(int4*)&sB[0][row][c8] = *(const int4*)&Bh[g];
            *(int4*)&sB[1][row][c8] = *(const int4*)&Bl[g];
        }
        __syncthreads();
        const int rb = wave * 32;
#pragma unroll
        for (int kk = 0; kk < 2; ++kk) {
            int ko = kk * 32 + lquad * 8;
            short8 ah[2], al[2], bh[4], bl[4];
#pragma unroll
            for (int i = 0; i < 2; ++i) {
                ah[i] = *(const short8*)&sA[0][rb + i * 16 + lrow][ko];
                al[i] = *(const short8*)&sA[1][rb + i * 16 + lrow][ko];
            }
#pragma unroll
            for (int j = 0; j < 4; ++j) {
                bh[j] = *(const short8*)&sB[0][j * 16 + lrow][ko];
                bl[j] = *(const short8*)&sB[1][j * 16 + lrow][ko];
            }
#pragma unroll
            for (int i = 0; i < 2; ++i)
#pragma unroll
                for (int j = 0; j < 4; ++j) {
                    acc[i][j] = __builtin_amdgcn_mfma_f32_16x16x32_bf16(
                        ah[i], bh[j], acc[i][j], 0, 0, 0);
                    acc[i][j] = __builtin_amdgcn_mfma_f32_16x16x32_bf16(
                        ah[i], bl[j], acc[i][j], 0, 0, 0);
                    acc[i][j] = __builtin_amdgcn_mfma_f32_16x16x32_bf16(
                        al[i], bh[j], acc[i][j], 0, 0, 0);
                }
        }
        __syncthreads();
    }
    float sj[4] = {0.f, 0.f, 0.f, 0.f};
    float qj[4] = {0.f, 0.f, 0.f, 0.f};
#pragma unroll
    for (int i = 0; i < 2; ++i)
#pragma unroll
        for (int j = 0; j < 4; ++j) {
            int gc = bn + j * 16 + lrow;
            float bv = bias[gc];
#pragma unroll
            for (int r = 0; r < 4; ++r) {
                int gr = bm + wave * 32 + i * 16 + lquad * 4 + r;
                float v = acc[i][j][r] + bv;
                if (relu) v = fmaxf(v, 0.f);
                if (STATS && gr < Nreal) {
                    sj[j] += v;
                    qj[j] = fmaf(v, v, qj[j]);
                }
                if (WRITE_BF16) {
                    ushort hv = f2bf_rne(v);
                    float hf = __uint_as_float(((unsigned)hv) << 16);
                    ushort lv = f2bf_rne(v - hf);
                    Chi[(size_t)gr * N + gc] = hv;
                    Clo[(size_t)gr * N + gc] = lv;
                } else {
                    Cf[(size_t)gr * N + gc] = v;
                }
            }
        }
    if (STATS) {
#pragma unroll
        for (int j = 0; j < 4; ++j) {
            float s = sj[j], q = qj[j];
            s += __shfl_xor(s, 16);
            s += __shfl_xor(s, 32);
            q += __shfl_xor(q, 16);
            q += __shfl_xor(q, 32);
            if (lquad == 0) {
                int gc = bn + j * 16 + lrow;
                atomicAdd(&stats[gc], s);
                atomicAdd(&stats[N + gc], q);
            }
        }
    }
}

// ---------------- BatchNorm apply ----------------
__global__ __launch_bounds__(256) void bn_apply_kernel(
    const float* __restrict__ r, float* __restrict__ h,
    const float* __restrict__ sums,
    const float* __restrict__ g, const float* __restrict__ bt,
    int N, int D, int Dm1) {
    int idx = blockIdx.x * blockDim.x + threadIdx.x;
    int total = N * D;
    int stride = gridDim.x * blockDim.x;
    float invN = 1.0f / (float)N;
    for (; idx < total; idx += stride) {
        int c = idx & Dm1;
        float mu = sums[c] * invN;
        float var = fmaf(-mu, mu, sums[D + c] * invN);
        float sc = rsqrtf(var + 1e-5f) * g[c];
        h[idx] = (r[idx] - mu) * sc + bt[c];
    }
}

// ---------------- Head ----------------
__global__ void head_kernel(const float* __restrict__ h, const int* __restrict__ n_nodes,
                            const float* __restrict__ Wf1, const float* __restrict__ bf1,
                            const float* __restrict__ Wf2, const float* __restrict__ bf2,
                            float* __restrict__ out, int G) {
    int g = blockIdx.x * blockDim.x + threadIdx.x;
    if (g >= G) return;
    int s = 0;
    for (int i = 0; i <= g; ++i) s += n_nodes[i];
    const float* m = &h[(size_t)(s - 1) * 64];
    float o = bf2[0];
#pragma unroll 4
    for (int j = 0; j < 16; ++j) {
        float acc = bf1[j];
        for (int k = 0; k < 64; ++k) acc = fmaf(m[k], Wf1[k * 16 + j], acc);
        acc = fmaxf(acc, 0.f);
        o = fmaf(acc, Wf2[j], o);
    }
    out[g] = o;
}

extern "C" void kernel_launch(void* const* d_in, const int* in_sizes, int n_in,
                              void* d_out, int out_size, void* d_ws, size_t ws_size,
                              hipStream_t stream) {
    const float* x = (const float*)d_in[0];
    const float* ea = (const float*)d_in[1];
    const int* eidx = (const int*)d_in[2];
    const int* n_nodes = (const int*)d_in[3];
    const float* We1 = (const float*)d_in[4];
    const float* be1 = (const float*)d_in[5];
    const float* W11 = (const float*)d_in[6];
    const float* b11 = (const float*)d_in[7];
    const float* W12 = (const float*)d_in[8];
    const float* b12 = (const float*)d_in[9];
    const float* g1 = (const float*)d_in[10];
    const float* bt1 = (const float*)d_in[11];
    const float* We2 = (const float*)d_in[12];
    const float* be2 = (const float*)d_in[13];
    const float* W21 = (const float*)d_in[14];
    const float* b21 = (const float*)d_in[15];
    const float* W22 = (const float*)d_in[16];
    const float* b22 = (const float*)d_in[17];
    const float* g2 = (const float*)d_in[18];
    const float* bt2 = (const float*)d_in[19];
    const float* We3 = (const float*)d_in[20];
    const float* be3 = (const float*)d_in[21];
    const float* W31 = (const float*)d_in[22];
    const float* b31 = (const float*)d_in[23];
    const float* W32 = (const float*)d_in[24];
    const float* b32 = (const float*)d_in[25];
    const float* g3 = (const float*)d_in[26];
    const float* bt3 = (const float*)d_in[27];
    const float* Wf1 = (const float*)d_in[28];
    const float* bf1 = (const float*)d_in[29];
    const float* Wf2 = (const float*)d_in[30];
    const float* bf2 = (const float*)d_in[31];

    const int N = in_sizes[0] / 128;  // 50000
    const int E = in_sizes[2] / 2;    // 800000
    const int G = in_sizes[3];        // 500
    const int Mp = ((N + 127) / 128) * 128;  // 50048
    const int* srcp = eidx;
    const int* dstp = eidx + E;

    float* H = (float*)d_ws;            // Mp x 256 fp32
    float* UR = H + (size_t)Mp * 256;   // Mp x 256: u(hi/lo bf16) / r(fp32)
    float* TT = UR + (size_t)Mp * 256;  // Mp x 256: t(hi/lo bf16)
    // zero region: stats (896 floats) + deg/cursor (2N ints), contiguous
    float* stats1 = TT + (size_t)Mp * 256;  // 512
    float* stats2 = stats1 + 512;           // 256
    float* stats3 = stats2 + 256;           // 128
    int* deg = (int*)(stats3 + 128);        // N
    int* cursor = deg + N;                  // N
    int* row_start = cursor + N;            // N+1
    int* csr_eid = row_start + N + 1;       // E
    int* csr_src = csr_eid + E;             // E
    // 16B-align the ushort weight region
    size_t woff = (size_t)(csr_src + E - (int*)d_ws);
    woff = (woff + 3) & ~(size_t)3;
    ushort* wp = (ushort*)((int*)d_ws + woff);
    ushort* W11th = wp; wp += 128 * 256;
    ushort* W11tl = wp; wp += 128 * 256;
    ushort* W12th = wp; wp += 256 * 256;
    ushort* W12tl = wp; wp += 256 * 256;
    ushort* W21th = wp; wp += 256 * 128;
    ushort* W21tl = wp; wp += 256 * 128;
    ushort* W22th = wp; wp += 128 * 128;
    ushort* W22tl = wp; wp += 128 * 128;
    ushort* W31th = wp; wp += 128 * 64;
    ushort* W31tl = wp; wp += 128 * 64;
    ushort* W32th = wp; wp += 64 * 64;
    ushort* W32tl = wp; wp += 64 * 64;

    hipMemsetAsync(stats1, 0, 896 * sizeof(float) + (size_t)2 * N * sizeof(int), stream);

    // ---------------- Weight prep (1 launch) ----------------
    const int prepTot = 128 * 256 + 256 * 256 + 256 * 128 + 128 * 128 + 128 * 64 + 64 * 64;
    prep_all<<<(prepTot + 255) / 256, 256, 0, stream>>>(
        W11, W11th, W11tl, W12, W12th, W12tl, W21, W21th, W21tl,
        W22, W22th, W22tl, W31, W31th, W31tl, W32, W32th, W32tl);

    // ---------------- CSR build ----------------
    hist_kernel<<<3125, 256, 0, stream>>>(dstp, deg, E);
    scan_kernel<<<1, 1024, 0, stream>>>(deg, row_start, N);
    scatter_kernel<<<3125, 256, 0, stream>>>(srcp, dstp, row_start, cursor,
                                             csr_eid, csr_src, E);

    const int aggBlocks = (N + 3) / 4;
    const int gy = Mp / 128;
    float* R = UR;

    // ---------------- Layer 1: 128 -> 256 -> 256 ----------------
    {
        ushort* Uhi = (ushort*)UR; ushort* Ulo = Uhi + (size_t)Mp * 128;
        ushort* Thi = (ushort*)TT; ushort* Tlo = Thi + (size_t)Mp * 256;
        gine_agg_kernel<128><<<aggBlocks, 256, 0, stream>>>(
            x, ea, row_start, csr_eid, csr_src, We1, be1, Uhi, Ulo, N);
        gemm_mfma<1, 0><<<dim3(4, gy), 256, 0, stream>>>(
            Uhi, Ulo, W11th, W11tl, b11, nullptr, Thi, Tlo, nullptr, 0, 256, 128, 1);
        gemm_mfma<0, 1><<<dim3(4, gy), 256, 0, stream>>>(
            Thi, Tlo, W12th, W12tl, b12, R, nullptr, nullptr, stats1, N, 256, 256, 1);
        bn_apply_kernel<<<2048, 256, 0, stream>>>(R, H, stats1, g1, bt1, N, 256, 255);
    }

    // ---------------- Layer 2: 256 -> 128 -> 128 ----------------
    {
        ushort* Uhi = (ushort*)UR; ushort* Ulo = Uhi + (size_t)Mp * 256;
        ushort* Thi = (ushort*)TT; ushort* Tlo = Thi + (size_t)Mp * 128;
        gine_agg_kernel<256><<<aggBlocks, 256, 0, stream>>>(
            H, ea, row_start, csr_eid, csr_src, We2, be2, Uhi, Ulo, N);
        gemm_mfma<1, 0><<<dim3(2, gy), 256, 0, stream>>>(
            Uhi, Ulo, W21th, W21tl, b21, nullptr, Thi, Tlo, nullptr, 0, 128, 256, 1);
        gemm_mfma<0, 1><<<dim3(2, gy), 256, 0, stream>>>(
            Thi, Tlo, W22th, W22tl, b22, R, nullptr, nullptr, stats2, N, 128, 128, 1);
        bn_apply_kernel<<<2048, 256, 0, stream>>>(R, H, stats2, g2, bt2, N, 128, 127);
    }

    // ---------------- Layer 3: 128 -> 64 -> 64 ----------------
    {
        ushort* Uhi = (ushort*)UR; ushort* Ulo = Uhi + (size_t)Mp * 128;
        ushort* Thi = (ushort*)TT; ushort* Tlo = Thi + (size_t)Mp * 64;
        gine_agg_kernel<128><<<aggBlocks, 256, 0, stream>>>(
            H, ea, row_start, csr_eid, csr_src, We3, be3, Uhi, Ulo, N);
        gemm_mfma<1, 0><<<dim3(1, gy), 256, 0, stream>>>(
            Uhi, Ulo, W31th, W31tl, b31, nullptr, Thi, Tlo, nullptr, 0, 64, 128, 1);
        gemm_mfma<0, 1><<<dim3(1, gy), 256, 0, stream>>>(
            Thi, Tlo, W32th, W32tl, b32, R, nullptr, nullptr, stats3, N, 64, 64, 1);
        bn_apply_kernel<<<2048, 256, 0, stream>>>(R, H, stats3, g3, bt3, N, 64, 63);
    }

    // ---------------- Head ----------------
    head_kernel<<<(G + 255) / 256, 256, 0, stream>>>(H, n_nodes, Wf1, bf1, Wf2, bf2,
                                                     (float*)d_out, G);
}

// Round 6
// 1008.917 us; speedup vs baseline: 2.2408x; 1.0461x over previous
//
#include <hip/hip_runtime.h>
#include <hip/hip_bf16.h>

// ---------------------------------------------------------------------------
// GIN0 (GINE x3 + BN + head) forward.
// R1: CSR + per-node register aggregation (no atomics in hot path).
// R3: node MLP GEMMs on MFMA via split-bf16 (hi+lo, 3-pass).
// R5: BN stats fused into GEMM2 epilogue; single prep kernel.
// R6: gathers read a bf16 copy of h (half the gather bytes/transactions --
//     agg was 88% memory-time at 452MB L2-miss). Self-term stays fp32.
//     Lane-contiguous channel ownership: 1 ushort4 gather/row/lane.
// ---------------------------------------------------------------------------

typedef __attribute__((ext_vector_type(8))) short short8;
typedef __attribute__((ext_vector_type(4))) float floatx4;
typedef __attribute__((ext_vector_type(2))) float float2v;

__device__ __forceinline__ float2v splat2(float s) {
    float2v v; v[0] = s; v[1] = s; return v;
}

__device__ __forceinline__ ushort f2bf_rne(float x) {
    unsigned u = __float_as_uint(x);
    unsigned r = (u + 0x7FFFu + ((u >> 16) & 1u)) >> 16;
    return (ushort)r;
}

__device__ __forceinline__ float bf2f(ushort u) {
    return __uint_as_float(((unsigned)u) << 16);
}

// ---------------- CSR build ----------------

__global__ __launch_bounds__(256) void hist_kernel(const int* __restrict__ dst,
                                                   int* __restrict__ deg, int E) {
    int i = blockIdx.x * blockDim.x + threadIdx.x;
    int stride = gridDim.x * blockDim.x;
    for (; i < E; i += stride) atomicAdd(&deg[dst[i]], 1);
}

__global__ __launch_bounds__(1024) void scan_kernel(const int* __restrict__ deg,
                                                    int* __restrict__ row_start, int N) {
    __shared__ int part[1024];
    int tid = threadIdx.x;
    int per = (N + 1023) / 1024;
    int start = tid * per;
    int end = min(start + per, N);
    int s = 0;
    for (int i = start; i < end; ++i) s += deg[i];
    part[tid] = s;
    __syncthreads();
    if (tid == 0) {
        int t = 0;
        for (int i = 0; i < 1024; ++i) {
            int v = part[i];
            part[i] = t;
            t += v;
        }
    }
    __syncthreads();
    int run = part[tid];
    for (int i = start; i < end; ++i) {
        row_start[i] = run;
        run += deg[i];
    }
    if (tid == 1023) row_start[N] = run;
}

__global__ __launch_bounds__(256) void scatter_kernel(
    const int* __restrict__ src, const int* __restrict__ dst,
    const int* __restrict__ row_start, int* __restrict__ cursor,
    int* __restrict__ csr_eid, int* __restrict__ csr_src, int E) {
    int i = blockIdx.x * blockDim.x + threadIdx.x;
    int stride = gridDim.x * blockDim.x;
    for (; i < E; i += stride) {
        int v = dst[i];
        int p = row_start[v] + atomicAdd(&cursor[v], 1);
        csr_eid[p] = i;
        csr_src[p] = src[i];
    }
}

// ---------------- Weight prep ----------------
__device__ __forceinline__ void wsplit(const float* W, ushort* Wth, ushort* Wtl,
                                       int K, int N, int t) {
    int k = t / N, n = t - k * N;
    float v = W[t];
    ushort hv = f2bf_rne(v);
    float hf = bf2f(hv);
    ushort lv = f2bf_rne(v - hf);
    Wth[(size_t)n * K + k] = hv;
    Wtl[(size_t)n * K + k] = lv;
}

__global__ __launch_bounds__(256) void prep_all(
    const float* W11, ushort* W11h, ushort* W11l,
    const float* W12, ushort* W12h, ushort* W12l,
    const float* W21, ushort* W21h, ushort* W21l,
    const float* W22, ushort* W22h, ushort* W22l,
    const float* W31, ushort* W31h, ushort* W31l,
    const float* W32, ushort* W32h, ushort* W32l) {
    int t = blockIdx.x * blockDim.x + threadIdx.x;
    const int s1 = 128 * 256, s2 = s1 + 256 * 256, s3 = s2 + 256 * 128;
    const int s4 = s3 + 128 * 128, s5 = s4 + 128 * 64, s6 = s5 + 64 * 64;
    if (t < s1) wsplit(W11, W11h, W11l, 128, 256, t);
    else if (t < s2) wsplit(W12, W12h, W12l, 256, 256, t - s1);
    else if (t < s3) wsplit(W21, W21h, W21l, 256, 128, t - s2);
    else if (t < s4) wsplit(W22, W22h, W22l, 128, 128, t - s3);
    else if (t < s5) wsplit(W31, W31h, W31l, 128, 64, t - s4);
    else if (t < s6) wsplit(W32, W32h, W32l, 64, 64, t - s5);
}

// ---------------- fp32 -> bf16 convert (layer-1 gather copy) --------------
__global__ __launch_bounds__(256) void f32_to_bf16(const float* __restrict__ in,
                                                   ushort* __restrict__ out, long n4) {
    long i = (long)blockIdx.x * blockDim.x + threadIdx.x;
    long stride = (long)gridDim.x * blockDim.x;
    for (; i < n4; i += stride) {
        float4 v = ((const float4*)in)[i];
        ushort4 o;
        o.x = f2bf_rne(v.x);
        o.y = f2bf_rne(v.y);
        o.z = f2bf_rne(v.z);
        o.w = f2bf_rne(v.w);
        ((ushort4*)out)[i] = o;
    }
}

// ---------------- Fused GINE aggregation ----------------
// One wave per node. Lane owns CPL = D/64 contiguous channels. Gathers come
// from the bf16 copy hb (1 vector load/row/lane); self-term from fp32 h.
template <int D>
__global__ __launch_bounds__(256) void gine_agg_kernel(
    const float* __restrict__ h, const ushort* __restrict__ hb,
    const float* __restrict__ ea,
    const int* __restrict__ row_start, const int* __restrict__ csr_eid,
    const int* __restrict__ csr_src,
    const float* __restrict__ We, const float* __restrict__ be,
    ushort* __restrict__ uhi, ushort* __restrict__ ulo, int N) {
    constexpr int CPL = D / 64;  // channels per lane (2 or 4)
    constexpr int C2 = CPL / 2;  // float2 chunks
    const int lane = threadIdx.x & 63;
    const int ch0 = lane * CPL;

    float2v w[16][C2];
#pragma unroll
    for (int k = 0; k < 16; ++k)
#pragma unroll
        for (int c = 0; c < C2; ++c)
            w[k][c] = *(const float2v*)&We[k * D + ch0 + 2 * c];
    float2v bias[C2];
#pragma unroll
    for (int c = 0; c < C2; ++c) bias[c] = *(const float2v*)&be[ch0 + 2 * c];

    int v = blockIdx.x * 4 + (threadIdx.x >> 6);
    const int vstride = gridDim.x * 4;
    const float2v z2 = splat2(0.f);

    for (; v < N; v += vstride) {
        int e0 = row_start[v];
        int e1 = row_start[v + 1];
        float2v acc[C2];
#pragma unroll
        for (int c = 0; c < C2; ++c) acc[c] = z2;

        int i = e0;
        for (; i + 4 <= e1; i += 4) {
            int myeid = csr_eid[i + (lane >> 4)];
            float eav = ea[(size_t)myeid * 16 + (lane & 15)];
            int se[4];
            se[0] = csr_src[i + 0];
            se[1] = csr_src[i + 1];
            se[2] = csr_src[i + 2];
            se[3] = csr_src[i + 3];
            float2v hv[4][C2];
#pragma unroll
            for (int e = 0; e < 4; ++e) {
                if (CPL == 4) {
                    ushort4 r = *(const ushort4*)&hb[(size_t)se[e] * D + ch0];
                    hv[e][0][0] = bf2f(r.x);
                    hv[e][0][1] = bf2f(r.y);
                    hv[e][C2 - 1][0] = bf2f(r.z);
                    hv[e][C2 - 1][1] = bf2f(r.w);
                } else {
                    ushort2 r = *(const ushort2*)&hb[(size_t)se[e] * D + ch0];
                    hv[e][0][0] = bf2f(r.x);
                    hv[e][0][1] = bf2f(r.y);
                }
            }
#pragma unroll
            for (int e = 0; e < 4; ++e) {
                float wk[16];
#pragma unroll
                for (int k = 0; k < 16; ++k)
                    wk[k] = __int_as_float(
                        __builtin_amdgcn_readlane(__float_as_int(eav), e * 16 + k));
#pragma unroll
                for (int c = 0; c < C2; ++c) {
                    float2v p = bias[c];
#pragma unroll
                    for (int k = 0; k < 16; ++k)
                        p = __builtin_elementwise_fma(splat2(wk[k]), w[k][c], p);
                    float2v m = p + hv[e][c];
                    acc[c] += __builtin_elementwise_max(m, z2);
                }
            }
        }
        for (; i < e1; ++i) {
            int eid = csr_eid[i];
            int s = csr_src[i];
            float eav = (lane < 16) ? ea[(size_t)eid * 16 + lane] : 0.f;
            float wk[16];
#pragma unroll
            for (int k = 0; k < 16; ++k)
                wk[k] = __int_as_float(
                    __builtin_amdgcn_readlane(__float_as_int(eav), k));
            float2v hv[C2];
            if (CPL == 4) {
                ushort4 r = *(const ushort4*)&hb[(size_t)s * D + ch0];
                hv[0][0] = bf2f(r.x);
                hv[0][1] = bf2f(r.y);
                hv[C2 - 1][0] = bf2f(r.z);
                hv[C2 - 1][1] = bf2f(r.w);
            } else {
                ushort2 r = *(const ushort2*)&hb[(size_t)s * D + ch0];
                hv[0][0] = bf2f(r.x);
                hv[0][1] = bf2f(r.y);
            }
#pragma unroll
            for (int c = 0; c < C2; ++c) {
                float2v p = bias[c];
#pragma unroll
                for (int k = 0; k < 16; ++k)
                    p = __builtin_elementwise_fma(splat2(wk[k]), w[k][c], p);
                float2v m = p + hv[c];
                acc[c] += __builtin_elementwise_max(m, z2);
            }
        }
        ushort hi[CPL], lo[CPL];
#pragma unroll
        for (int c = 0; c < C2; ++c) {
            float2v sv = *(const float2v*)&h[(size_t)v * D + ch0 + 2 * c];
#pragma unroll
            for (int j = 0; j < 2; ++j) {
                float uv = sv[j] + acc[c][j];
                ushort hu = f2bf_rne(uv);
                ushort lu = f2bf_rne(uv - bf2f(hu));
                hi[2 * c + j] = hu;
                lo[2 * c + j] = lu;
            }
        }
        if (CPL == 4) {
            *(ushort4*)&uhi[(size_t)v * D + ch0] =
                make_ushort4(hi[0], hi[1], hi[CPL - 2], hi[CPL - 1]);
            *(ushort4*)&ulo[(size_t)v * D + ch0] =
                make_ushort4(lo[0], lo[1], lo[CPL - 2], lo[CPL - 1]);
        } else {
            *(ushort2*)&uhi[(size_t)v * D + ch0] = make_ushort2(hi[0], hi[1]);
            *(ushort2*)&ulo[(size_t)v * D + ch0] = make_ushort2(lo[0], lo[1]);
        }
    }
}

// ---------------- Split-bf16 MFMA GEMM (+ optional fused BN stats) ---------
template <int WRITE_BF16, int STATS>
__global__ __launch_bounds__(256) void gemm_mfma(
    const ushort* __restrict__ Ah, const ushort* __restrict__ Al,
    const ushort* __restrict__ Bh, const ushort* __restrict__ Bl,
    const float* __restrict__ bias,
    float* __restrict__ Cf, ushort* __restrict__ Chi, ushort* __restrict__ Clo,
    float* __restrict__ stats, int Nreal,
    int N, int K, int relu) {
    __shared__ ushort sA[2][128][72];
    __shared__ ushort sB[2][64][72];
    const int tid = threadIdx.x;
    const int wave = tid >> 6, lane = tid & 63;
    const int lrow = lane & 15, lquad = lane >> 4;
    const int bm = blockIdx.y * 128;
    const int bn = blockIdx.x * 64;

    floatx4 acc[2][4];
#pragma unroll
    for (int i = 0; i < 2; ++i)
#pragma unroll
        for (int j = 0; j < 4; ++j) acc[i][j] = (floatx4)0.f;

    for (int k0 = 0; k0 < K; k0 += 64) {
        for (int s = tid; s < 1024; s += 256) {
            int row = s >> 3, c8 = (s & 7) * 8;
            size_t g = (size_t)(bm + row) * K + k0 + c8;
            *(int4*)&sA[0][row][c8] = *(const int4*)&Ah[g];
            *(int4*)&sA[1][row][c8] = *(const int4*)&Al[g];
        }
        for (int s = tid; s < 512; s += 256) {
            int row = s >> 3, c8 = (s & 7) * 8;
            size_t g = (size_t)(bn + row) * K + k0 + c8;
            *(int4*)&sB[0][row][c8] = *(const int4*)&Bh[g];
            *(int4*)&sB[1][row][c8] = *(const int4*)&Bl[g];
        }
        __syncthreads();
        const int rb = wave * 32;
#pragma unroll
        for (int kk = 0; kk < 2; ++kk) {
            int ko = kk * 32 + lquad * 8;
            short8 ah[2], al[2], bh[4], bl[4];
#pragma unroll
            for (int i = 0; i < 2; ++i) {
                ah[i] = *(const short8*)&sA[0][rb + i * 16 + lrow][ko];
                al[i] = *(const short8*)&sA[1][rb + i * 16 + lrow][ko];
            }
#pragma unroll
            for (int j = 0; j < 4; ++j) {
                bh[j] = *(const short8*)&sB[0][j * 16 + lrow][ko];
                bl[j] = *(const short8*)&sB[1][j * 16 + lrow][ko];
            }
#pragma unroll
            for (int i = 0; i < 2; ++i)
#pragma unroll
                for (int j = 0; j < 4; ++j) {
                    acc[i][j] = __builtin_amdgcn_mfma_f32_16x16x32_bf16(
                        ah[i], bh[j], acc[i][j], 0, 0, 0);
                    acc[i][j] = __builtin_amdgcn_mfma_f32_16x16x32_bf16(
                        ah[i], bl[j], acc[i][j], 0, 0, 0);
                    acc[i][j] = __builtin_amdgcn_mfma_f32_16x16x32_bf16(
                        al[i], bh[j], acc[i][j], 0, 0, 0);
                }
        }
        __syncthreads();
    }
    float sj[4] = {0.f, 0.f, 0.f, 0.f};
    float qj[4] = {0.f, 0.f, 0.f, 0.f};
#pragma unroll
    for (int i = 0; i < 2; ++i)
#pragma unroll
        for (int j = 0; j < 4; ++j) {
            int gc = bn + j * 16 + lrow;
            float bv = bias[gc];
#pragma unroll
            for (int r = 0; r < 4; ++r) {
                int gr = bm + wave * 32 + i * 16 + lquad * 4 + r;
                float v = acc[i][j][r] + bv;
                if (relu) v = fmaxf(v, 0.f);
                if (STATS && gr < Nreal) {
                    sj[j] += v;
                    qj[j] = fmaf(v, v, qj[j]);
                }
                if (WRITE_BF16) {
                    ushort hv = f2bf_rne(v);
                    ushort lv = f2bf_rne(v - bf2f(hv));
                    Chi[(size_t)gr * N + gc] = hv;
                    Clo[(size_t)gr * N + gc] = lv;
                } else {
                    Cf[(size_t)gr * N + gc] = v;
                }
            }
        }
    if (STATS) {
#pragma unroll
        for (int j = 0; j < 4; ++j) {
            float s = sj[j], q = qj[j];
            s += __shfl_xor(s, 16);
            s += __shfl_xor(s, 32);
            q += __shfl_xor(q, 16);
            q += __shfl_xor(q, 32);
            if (lquad == 0) {
                int gc = bn + j * 16 + lrow;
                atomicAdd(&stats[gc], s);
                atomicAdd(&stats[N + gc], q);
            }
        }
    }
}

// ---------------- BatchNorm apply (+ bf16 copy for next gather) ------------
__global__ __launch_bounds__(256) void bn_apply_kernel(
    const float* __restrict__ r, float* __restrict__ h,
    ushort* __restrict__ hbout,
    const float* __restrict__ sums,
    const float* __restrict__ g, const float* __restrict__ bt,
    int N, int D, int Dm1) {
    int idx = blockIdx.x * blockDim.x + threadIdx.x;
    int total = N * D;
    int stride = gridDim.x * blockDim.x;
    float invN = 1.0f / (float)N;
    for (; idx < total; idx += stride) {
        int c = idx & Dm1;
        float mu = sums[c] * invN;
        float var = fmaf(-mu, mu, sums[D + c] * invN);
        float sc = rsqrtf(var + 1e-5f) * g[c];
        float val = (r[idx] - mu) * sc + bt[c];
        h[idx] = val;
        if (hbout) hbout[idx] = f2bf_rne(val);
    }
}

// ---------------- Head ----------------
__global__ void head_kernel(const float* __restrict__ h, const int* __restrict__ n_nodes,
                            const float* __restrict__ Wf1, const float* __restrict__ bf1,
                            const float* __restrict__ Wf2, const float* __restrict__ bf2,
                            float* __restrict__ out, int G) {
    int g = blockIdx.x * blockDim.x + threadIdx.x;
    if (g >= G) return;
    int s = 0;
    for (int i = 0; i <= g; ++i) s += n_nodes[i];
    const float* m = &h[(size_t)(s - 1) * 64];
    float o = bf2[0];
#pragma unroll 4
    for (int j = 0; j < 16; ++j) {
        float acc = bf1[j];
        for (int k = 0; k < 64; ++k) acc = fmaf(m[k], Wf1[k * 16 + j], acc);
        acc = fmaxf(acc, 0.f);
        o = fmaf(acc, Wf2[j], o);
    }
    out[g] = o;
}

extern "C" void kernel_launch(void* const* d_in, const int* in_sizes, int n_in,
                              void* d_out, int out_size, void* d_ws, size_t ws_size,
                              hipStream_t stream) {
    const float* x = (const float*)d_in[0];
    const float* ea = (const float*)d_in[1];
    const int* eidx = (const int*)d_in[2];
    const int* n_nodes = (const int*)d_in[3];
    const float* We1 = (const float*)d_in[4];
    const float* be1 = (const float*)d_in[5];
    const float* W11 = (const float*)d_in[6];
    const float* b11 = (const float*)d_in[7];
    const float* W12 = (const float*)d_in[8];
    const float* b12 = (const float*)d_in[9];
    const float* g1 = (const float*)d_in[10];
    const float* bt1 = (const float*)d_in[11];
    const float* We2 = (const float*)d_in[12];
    const float* be2 = (const float*)d_in[13];
    const float* W21 = (const float*)d_in[14];
    const float* b21 = (const float*)d_in[15];
    const float* W22 = (const float*)d_in[16];
    const float* b22 = (const float*)d_in[17];
    const float* g2 = (const float*)d_in[18];
    const float* bt2 = (const float*)d_in[19];
    const float* We3 = (const float*)d_in[20];
    const float* be3 = (const float*)d_in[21];
    const float* W31 = (const float*)d_in[22];
    const float* b31 = (const float*)d_in[23];
    const float* W32 = (const float*)d_in[24];
    const float* b32 = (const float*)d_in[25];
    const float* g3 = (const float*)d_in[26];
    const float* bt3 = (const float*)d_in[27];
    const float* Wf1 = (const float*)d_in[28];
    const float* bf1 = (const float*)d_in[29];
    const float* Wf2 = (const float*)d_in[30];
    const float* bf2 = (const float*)d_in[31];

    const int N = in_sizes[0] / 128;  // 50000
    const int E = in_sizes[2] / 2;    // 800000
    const int G = in_sizes[3];        // 500
    const int Mp = ((N + 127) / 128) * 128;  // 50048
    const int* srcp = eidx;
    const int* dstp = eidx + E;

    float* H = (float*)d_ws;            // Mp x 256 fp32
    float* UR = H + (size_t)Mp * 256;   // Mp x 256: u(hi/lo bf16) / r(fp32)
    float* TT = UR + (size_t)Mp * 256;  // Mp x 256: t(hi/lo bf16) / hb(bf16)
    float* stats1 = TT + (size_t)Mp * 256;  // 512
    float* stats2 = stats1 + 512;           // 256
    float* stats3 = stats2 + 256;           // 128
    int* deg = (int*)(stats3 + 128);        // N
    int* cursor = deg + N;                  // N
    int* row_start = cursor + N;            // N+1
    int* csr_eid = row_start + N + 1;       // E
    int* csr_src = csr_eid + E;             // E
    size_t woff = (size_t)(csr_src + E - (int*)d_ws);
    woff = (woff + 3) & ~(size_t)3;
    ushort* wp = (ushort*)((int*)d_ws + woff);
    ushort* W11th = wp; wp += 128 * 256;
    ushort* W11tl = wp; wp += 128 * 256;
    ushort* W12th = wp; wp += 256 * 256;
    ushort* W12tl = wp; wp += 256 * 256;
    ushort* W21th = wp; wp += 256 * 128;
    ushort* W21tl = wp; wp += 256 * 128;
    ushort* W22th = wp; wp += 128 * 128;
    ushort* W22tl = wp; wp += 128 * 128;
    ushort* W31th = wp; wp += 128 * 64;
    ushort* W31tl = wp; wp += 128 * 64;
    ushort* W32th = wp; wp += 64 * 64;
    ushort* W32tl = wp; wp += 64 * 64;

    hipMemsetAsync(stats1, 0, 896 * sizeof(float) + (size_t)2 * N * sizeof(int), stream);

    const int prepTot = 128 * 256 + 256 * 256 + 256 * 128 + 128 * 128 + 128 * 64 + 64 * 64;
    prep_all<<<(prepTot + 255) / 256, 256, 0, stream>>>(
        W11, W11th, W11tl, W12, W12th, W12tl, W21, W21th, W21tl,
        W22, W22th, W22tl, W31, W31th, W31tl, W32, W32th, W32tl);

    hist_kernel<<<3125, 256, 0, stream>>>(dstp, deg, E);
    scan_kernel<<<1, 1024, 0, stream>>>(deg, row_start, N);
    scatter_kernel<<<3125, 256, 0, stream>>>(srcp, dstp, row_start, cursor,
                                             csr_eid, csr_src, E);

    const int aggBlocks = (N + 3) / 4;
    const int gy = Mp / 128;
    float* R = UR;
    ushort* HB = (ushort*)TT;  // bf16 gather copy lives in the (dead) TT region

    // ---------------- Layer 1: 128 -> 256 -> 256 ----------------
    {
        ushort* Uhi = (ushort*)UR; ushort* Ulo = Uhi + (size_t)Mp * 128;
        ushort* Thi = (ushort*)TT; ushort* Tlo = Thi + (size_t)Mp * 256;
        f32_to_bf16<<<2048, 256, 0, stream>>>(x, HB, (long)N * 128 / 4);
        gine_agg_kernel<128><<<aggBlocks, 256, 0, stream>>>(
            x, HB, ea, row_start, csr_eid, csr_src, We1, be1, Uhi, Ulo, N);
        gemm_mfma<1, 0><<<dim3(4, gy), 256, 0, stream>>>(
            Uhi, Ulo, W11th, W11tl, b11, nullptr, Thi, Tlo, nullptr, 0, 256, 128, 1);
        gemm_mfma<0, 1><<<dim3(4, gy), 256, 0, stream>>>(
            Thi, Tlo, W12th, W12tl, b12, R, nullptr, nullptr, stats1, N, 256, 256, 1);
        bn_apply_kernel<<<2048, 256, 0, stream>>>(R, H, HB, stats1, g1, bt1, N, 256, 255);
    }

    // ---------------- Layer 2: 256 -> 128 -> 128 ----------------
    {
        ushort* Uhi = (ushort*)UR; ushort* Ulo = Uhi + (size_t)Mp * 256;
        ushort* Thi = (ushort*)TT; ushort* Tlo = Thi + (size_t)Mp * 128;
        gine_agg_kernel<256><<<aggBlocks, 256, 0, stream>>>(
            H, HB, ea, row_start, csr_eid, csr_src, We2, be2, Uhi, Ulo, N);
        gemm_mfma<1, 0><<<dim3(2, gy), 256, 0, stream>>>(
            Uhi, Ulo, W21th, W21tl, b21, nullptr, Thi, Tlo, nullptr, 0, 128, 256, 1);
        gemm_mfma<0, 1><<<dim3(2, gy), 256, 0, stream>>>(
            Thi, Tlo, W22th, W22tl, b22, R, nullptr, nullptr, stats2, N, 128, 128, 1);
        bn_apply_kernel<<<2048, 256, 0, stream>>>(R, H, HB, stats2, g2, bt2, N, 128, 127);
    }

    // ---------------- Layer 3: 128 -> 64 -> 64 ----------------
    {
        ushort* Uhi = (ushort*)UR; ushort* Ulo = Uhi + (size_t)Mp * 128;
        ushort* Thi = (ushort*)TT; ushort* Tlo = Thi + (size_t)Mp * 64;
        gine_agg_kernel<128><<<aggBlocks, 256, 0, stream>>>(
            H, HB, ea, row_start, csr_eid, csr_src, We3, be3, Uhi, Ulo, N);
        gemm_mfma<1, 0><<<dim3(1, gy), 256, 0, stream>>>(
            Uhi, Ulo, W31th, W31tl, b31, nullptr, Thi, Tlo, nullptr, 0, 64, 128, 1);
        gemm_mfma<0, 1><<<dim3(1, gy), 256, 0, stream>>>(
            Thi, Tlo, W32th, W32tl, b32, R, nullptr, nullptr, stats3, N, 64, 64, 1);
        bn_apply_kernel<<<2048, 256, 0, stream>>>(R, H, nullptr, stats3, g3, bt3, N, 64, 63);
    }

    // ---------------- Head ----------------
    head_kernel<<<(G + 255) / 256, 256, 0, stream>>>(H, n_nodes, Wf1, bf1, Wf2, bf2,
                                                     (float*)d_out, G);
}